// Round 4
// baseline (2394.258 us; speedup 1.0000x reference)
//
#include <hip/hip_runtime.h>

// CauRecNet: 2-layer LSTM, B=131072 x T=15, i8-pair (14-bit fixed point) MFMA.
// Round 4: fused phase {L1(t) + L0(t+1)} -> 2 barriers/iter, within-wave
// MFMA/VALU overlap (1 block/CU is structural: ~228 unified regs/wave).
// (round-3 resubmit with the vector-element reference-bind compile fix)

typedef int   i32x4 __attribute__((ext_vector_type(4)));
typedef float f32x4 __attribute__((ext_vector_type(4)));

#define DEV static __device__ __forceinline__

DEV float fexp2(float x){ return __builtin_amdgcn_exp2f(x); }
DEV float frcp (float x){ return __builtin_amdgcn_rcpf(x); }

#define MFMA64(A,B,C) __builtin_amdgcn_mfma_i32_16x16x64_i8(A,B,C,0,0,0)
#define MFMA32(A,B,C) __builtin_amdgcn_mfma_i32_16x16x32_i8(A,B,C,0,0,0)

constexpr int T = 15, F = 12, CS = 96;
constexpr int R = 64;

// d_ws layout (bytes) — unchanged from round 2
constexpr int Q1OFF  = 0;        // W1 frags [8w][4g][3ks][2sp][64][16]
constexpr int Q0OFF  = 196608;   // W0 frags [4grp][4g]{x:2sp*512 | h:2sp*1024}
constexpr int QF2OFF = 245760;   // fc2 frags
constexpr int QF1OFF = 278528;   // fc1 frags
constexpr int S1OFF  = 294912;   // f32[512]
constexpr int S0OFF  = 296960;   // f32[256]
constexpr int SF2OFF = 297984;   // f32[128]
constexpr int SF1OFF = 298496;   // f32[64]

constexpr float QM   = 16128.0f;
constexpr float QMX  = 2016.0f;
constexpr float HINV = 1.0f/16128.0f;
constexpr float NL2E = -1.44269504f, PL2E2 = 2.88539008f;
constexpr float MAGIC = 12582912.0f;   // 1.5 * 2^23
constexpr int   MAGI  = 0x4B400000;

// unified LDS offsets
constexpr int O1L  = 16384;   // xh1l  (xh1h at 0; row stride 256)
constexpr int OXH  = 32768;   // x0h   (row stride 32)
constexpr int OXL  = 34816;   // x0l
constexpr int OWE  = 36864;   // wEff (floats)
constexpr int LDSB = OWE + 132*4;

// ---------------- weight pre-quantization (unchanged) ----------------
__global__ __launch_bounds__(64) void prequant(
    const float* __restrict__ fc1w, const float* __restrict__ fc2w,
    const float* __restrict__ w0i,  const float* __restrict__ w0h,
    const float* __restrict__ w1i,  const float* __restrict__ w1h,
    char* __restrict__ ws)
{
  const int r = blockIdx.x, j = threadIdx.x;
  float v[3] = {0.f, 0.f, 0.f};
  int   kk[3] = {-1, -1, -1};
  int type, n;
  if (r < 512){ type = 0; n = r; }
  else if (r < 768){ type = 1; n = r - 512; }
  else if (r < 896){ type = 2; n = r - 768; }
  else { type = 3; n = r - 896; }

  if (type == 0){
    for (int c = 0; c < 3; ++c){
      int k = j + c*64; kk[c] = k;
      v[c] = (k < 64) ? w1i[n*64 + k] : w1h[n*128 + (k - 64)];
    }
  } else if (type == 1){
    kk[0] = j;
    v[0] = (j < 32) ? ((j < 12) ? w0i[n*12 + j] : 0.f) : w0h[n*64 + (j - 32)];
    if (j < 32){ kk[1] = 64 + j; v[1] = w0h[n*64 + (32 + j)]; }
  } else {
    const float* fw = (type == 2) ? fc2w : fc1w;
    for (int c = 0; c < 2; ++c){
      int k = j + c*64; kk[c] = k;
      v[c] = (k < 96) ? fw[n*CS + k] : 0.f;
    }
  }
  float m = fmaxf(fmaxf(fabsf(v[0]), fabsf(v[1])), fabsf(v[2]));
  #pragma unroll
  for (int d = 32; d; d >>= 1) m = fmaxf(m, __shfl_xor(m, d));
  float s   = (m > 0.f) ? (m / 16120.0f) : 1.0f;
  float inv = (m > 0.f) ? (16120.0f / m) : 0.0f;
  if (j == 0){
    float* sp = (float*)(ws + (type==0 ? S1OFF : type==1 ? S0OFF : type==2 ? SF2OFF : SF1OFF));
    sp[n] = s;
  }
  const int lr = n & 15;
  #pragma unroll
  for (int c = 0; c < 3; ++c){
    int k = kk[c];
    if (k < 0) continue;
    float q  = rintf(v[c] * inv);
    float hf = rintf(q * 0.0078125f);
    int hi = (int)hf, lo = (int)(q - hf*128.0f);
    long offh, offl;
    if (type == 0){
      int g = n >> 7, wv = (n & 127) >> 4;
      int ks = k >> 6, lg = (k >> 4) & 3, jj = k & 15, lane = lg*16 + lr;
      long base = Q1OFF + (((long)((wv*4+g)*3+ks)*2*64) + lane)*16 + jj;
      offh = base; offl = base + 1024;
    } else if (type == 1){
      int g = n >> 6, grp = (n & 63) >> 4;
      long b0 = Q0OFF + (long)(grp*4+g)*3072;
      if (k < 32){ int lg = (k>>3)&3, jj = k&7, lane = lg*16+lr;
        offh = b0 + lane*8 + jj; offl = offh + 512;
      } else { int kh = k-32, lg = kh>>4, jj = kh&15, lane = lg*16+lr;
        offh = b0 + 1024 + lane*16 + jj; offl = offh + 1024;
      }
    } else {
      int ks = k >> 6, lg = (k>>4)&3, jj = k&15, lane = lg*16+lr;
      int grp = n >> 4;
      long base = (type==2 ? QF2OFF : QF1OFF) + ((long)((grp*2+ks)*2)*64 + lane)*16 + jj;
      offh = base; offl = base + 1024;
    }
    ws[offh] = (char)hi; ws[offl] = (char)lo;
  }
}

// ---------------- helpers ----------------
DEV unsigned pk4(int b0, int b1, int b2, int b3){
  unsigned p01 = __builtin_amdgcn_perm((unsigned)b1, (unsigned)b0, 0x00000400u);
  unsigned p23 = __builtin_amdgcn_perm((unsigned)b3, (unsigned)b2, 0x04000000u);
  return __builtin_amdgcn_perm(p23, p01, 0x07060100u);
}

DEV void cellupd(float t0, float t1, float t2, float t3,
                 float& c, int& hi, int& lo){
  float gi = frcp(1.f + fexp2(t0));
  float gf = frcp(1.f + fexp2(t1));
  float gg = fmaf(-2.f, frcp(1.f + fexp2(t2)), 1.f);
  float go = frcp(1.f + fexp2(t3));
  float tmp = fmaf(gf, c, gi*gg);
  c += tmp;
  float th = fmaf(-2.f, frcp(1.f + fexp2(tmp*PL2E2)), 1.f);
  int qi = __float_as_int(fmaf(go*th, QM, MAGIC)) - MAGI;
  hi = (qi + 64) >> 7;
  lo = qi - (hi << 7);
}

DEV unsigned quantw(float4 v, unsigned& lw){
  int h[4], l[4];
  float vv[4] = {v.x, v.y, v.z, v.w};
  #pragma unroll
  for (int e = 0; e < 4; ++e){
    int qi = __float_as_int(fmaf(vv[e], QMX, MAGIC)) - MAGI;
    h[e] = (qi + 64) >> 7;
    l[e] = qi - (h[e] << 7);
  }
  lw = pk4(l[0], l[1], l[2], l[3]);
  return pk4(h[0], h[1], h[2], h[3]);
}

// ---------------- main recurrence kernel ----------------
__global__ __launch_bounds__(512, 2) void caurec(
    const float* __restrict__ x,    const float* __restrict__ cs,
    const float* __restrict__ fc1b, const float* __restrict__ fc2b,
    const float* __restrict__ b0i,  const float* __restrict__ b0h,
    const float* __restrict__ b1i,  const float* __restrict__ b1h,
    const float* __restrict__ d1w,  const float* __restrict__ d1b,
    const float* __restrict__ d2w,  const float* __restrict__ d2b,
    const char* __restrict__ ws,    float* __restrict__ out)
{
  __shared__ alignas(16) char L[LDSB];

  const int tid  = threadIdx.x;
  const int wave = tid >> 6, lane = tid & 63, lr = lane & 15, lg = lane >> 4;
  const int n0   = (wave & 3) * 16, mB0 = (wave >> 2) * 32, n1 = wave * 16;
  const int grp  = wave & 3;
  const int rowBase = blockIdx.x * R;

  // precomputed per-lane LDS bases (compile-time immediates cover mt/ks/hi-lo)
  const int swzr = (lr & 7) << 4;
  int rdA[3];
  #pragma unroll
  for (int ks = 0; ks < 3; ++ks) rdA[ks] = lr*256 + ((ks*64 + lg*16) ^ swzr);
  const int rdA0 = rdA[0] + mB0*256;
  const int xrd  = OXH + (mB0 + lr)*32 + lg*8;
  int stA[4], stB[4];
  #pragma unroll
  for (int e = 0; e < 4; ++e){
    int rw = lg*4 + e, sz = (rw & 7) << 4;
    stA[e] = rw*256 + ((64 + n1 + lr) ^ sz);
    stB[e] = (mB0 + rw)*256 + ((n0 + lr) ^ sz);
  }
  const int xr = tid/3, xq = tid - (tid/3)*3;
  const int xst = OXH + xr*32 + xq*4;

  // ---- prologue: zero LDS
  #pragma unroll
  for (int i = tid; i < OWE/4; i += 512) ((unsigned*)L)[i] = 0u;
  __syncthreads();

  // stage cs -> logical cols [128,224) of xh1; stage x(0); wEff
  #pragma unroll
  for (int it = 0; it < 3; ++it){
    int u = tid + it*512, r = u/24, q = u - (u/24)*24;
    float4 v = *(const float4*)&cs[(size_t)(rowBase + r)*CS + q*4];
    unsigned lw, hw = quantw(v, lw);
    int ad = r*256 + ((128 + q*4) ^ ((r & 7) << 4));
    *(unsigned*)(L + ad) = hw; *(unsigned*)(L + ad + O1L) = lw;
  }
  if (tid < 192){
    float4 v = *(const float4*)&x[((size_t)(rowBase + xr)*T + 0)*F + xq*4];
    unsigned lw, hw = quantw(v, lw);
    *(unsigned*)(L + xst) = hw; *(unsigned*)(L + xst + 2048) = lw;
  }
  if (tid < 128){
    float s = 0.f;
    for (int a = 0; a < 64; ++a) s += d2w[a] * d1w[a*128 + tid];
    ((float*)(L + OWE))[tid] = s;
  } else if (tid == 128){
    float s = 0.f;
    for (int a = 0; a < 64; ++a) s += d2w[a] * d1b[a];
    ((float*)(L + OWE))[128] = s + d2b[0];
  }
  __syncthreads();

  // persistent weight fragments
  i32x4 WB1[4][3][2];
  #pragma unroll
  for (int g = 0; g < 4; ++g)
    #pragma unroll
    for (int ks = 0; ks < 3; ++ks)
      #pragma unroll
      for (int sp = 0; sp < 2; ++sp)
        WB1[g][ks][sp] = *(const i32x4*)(ws + Q1OFF + ((long)(((wave*4+g)*3+ks)*2+sp)*64 + lane)*16);
  i32x4 WB0h[4][2]; long WB0x[4][2];
  #pragma unroll
  for (int g = 0; g < 4; ++g){
    const char* b0p = ws + Q0OFF + (long)(grp*4+g)*3072;
    #pragma unroll
    for (int sp = 0; sp < 2; ++sp){
      WB0x[g][sp] = *(const long*)(b0p + sp*512 + lane*8);
      WB0h[g][sp] = *(const i32x4*)(b0p + 1024 + sp*1024 + lane*16);
    }
  }
  // folded gate constants: t = fma(fma(cvtB, 1/128, cvtA), kA, kC)
  float kA1[4], kC1[4], kA0[4], kC0[4];
  {
    const float* S1p = (const float*)(ws + S1OFF);
    const float* S0p = (const float*)(ws + S0OFF);
    #pragma unroll
    for (int g = 0; g < 4; ++g){
      float f = (g == 2) ? PL2E2 : NL2E;
      kA1[g] = f * 16384.f * (S1p[g*128 + n1 + lr] * HINV);
      kC1[g] = f * (b1i[g*128 + n1 + lr] + b1h[g*128 + n1 + lr]);
      kA0[g] = f * 16384.f * (S0p[g*64 + n0 + lr] * HINV);
      kC0[g] = f * (b0i[g*64 + n0 + lr] + b0h[g*64 + n0 + lr]);
    }
  }

  // init GEMMs: c1 = cs@fc2w^T + fc2b ; c0 = cs@fc1w^T + fc1b
  f32x4 c1r[4], c0r[2];
  {
    float sf2 = ((const float*)(ws + SF2OFF))[n1 + lr] * (HINV * 8.0f);
    float bb2 = fc2b[n1 + lr];
    #pragma unroll
    for (int mt = 0; mt < 4; ++mt){
      i32x4 aA = {0,0,0,0}, aB = {0,0,0,0};
      #pragma unroll
      for (int ks = 0; ks < 2; ++ks){
        int ad = lr*256 + (((128 + ks*64) + lg*16) ^ swzr) + mt*4096;
        i32x4 Ah = *(const i32x4*)(L + ad);
        i32x4 Al = *(const i32x4*)(L + ad + O1L);
        i32x4 Bh = *(const i32x4*)(ws + QF2OFF + ((long)((wave*2+ks)*2+0)*64 + lane)*16);
        i32x4 Bl = *(const i32x4*)(ws + QF2OFF + ((long)((wave*2+ks)*2+1)*64 + lane)*16);
        aA = MFMA64(Ah, Bh, aA); aB = MFMA64(Ah, Bl, aB); aB = MFMA64(Al, Bh, aB);
      }
      #pragma unroll
      for (int e = 0; e < 4; ++e)
        c1r[mt][e] = (16384.f*(float)aA[e] + 128.f*(float)aB[e])*sf2 + bb2;
    }
    float sf1 = ((const float*)(ws + SF1OFF))[n0 + lr] * (HINV * 8.0f);
    float bb1 = fc1b[n0 + lr];
    #pragma unroll
    for (int mt = 0; mt < 2; ++mt){
      i32x4 aA = {0,0,0,0}, aB = {0,0,0,0};
      #pragma unroll
      for (int ks = 0; ks < 2; ++ks){
        int ad = (mB0 + mt*16 + lr)*256 + (((128 + ks*64) + lg*16) ^ swzr);
        i32x4 Ah = *(const i32x4*)(L + ad);
        i32x4 Al = *(const i32x4*)(L + ad + O1L);
        i32x4 Bh = *(const i32x4*)(ws + QF1OFF + ((long)((grp*2+ks)*2+0)*64 + lane)*16);
        i32x4 Bl = *(const i32x4*)(ws + QF1OFF + ((long)((grp*2+ks)*2+1)*64 + lane)*16);
        aA = MFMA64(Ah, Bh, aA); aB = MFMA64(Ah, Bl, aB); aB = MFMA64(Al, Bh, aB);
      }
      #pragma unroll
      for (int e = 0; e < 4; ++e)
        c0r[mt][e] = (16384.f*(float)aA[e] + 128.f*(float)aB[e])*sf1 + bb1;
    }
  }
  __syncthreads();
  // re-zero cs staging region (h1 cols [64,160) for t=0)
  #pragma unroll
  for (int i = tid; i < 64*24; i += 512){
    int r = i/24, w = i - (i/24)*24;
    int ad = r*256 + ((128 + w*4) ^ ((r & 7) << 4));
    *(unsigned*)(L + ad) = 0u; *(unsigned*)(L + ad + O1L) = 0u;
  }
  __syncthreads();

  // L1 tile: MFMA + elementwise for one 16-row M-tile
  auto l1_one = [&](int mt, f32x4& c, unsigned& hw, unsigned& lw){
    i32x4 aA[4], aB[4];
    #pragma unroll
    for (int g = 0; g < 4; ++g){ aA[g] = i32x4{0,0,0,0}; aB[g] = i32x4{0,0,0,0}; }
    #pragma unroll
    for (int ks = 0; ks < 3; ++ks){
      i32x4 Hh = *(const i32x4*)(L + rdA[ks] + mt*4096);
      i32x4 Hl = *(const i32x4*)(L + rdA[ks] + mt*4096 + O1L);
      #pragma unroll
      for (int g = 0; g < 4; ++g){
        aA[g] = MFMA64(Hh, WB1[g][ks][0], aA[g]);
        aB[g] = MFMA64(Hh, WB1[g][ks][1], aB[g]);
        aB[g] = MFMA64(Hl, WB1[g][ks][0], aB[g]);
      }
    }
    int hb[4], lb[4];
    #pragma unroll
    for (int e = 0; e < 4; ++e){
      float t0 = fmaf(fmaf((float)aB[0][e], 0.0078125f, (float)aA[0][e]), kA1[0], kC1[0]);
      float t1 = fmaf(fmaf((float)aB[1][e], 0.0078125f, (float)aA[1][e]), kA1[1], kC1[1]);
      float t2 = fmaf(fmaf((float)aB[2][e], 0.0078125f, (float)aA[2][e]), kA1[2], kC1[2]);
      float t3 = fmaf(fmaf((float)aB[3][e], 0.0078125f, (float)aA[3][e]), kA1[3], kC1[3]);
      float cc = c[e];
      cellupd(t0, t1, t2, t3, cc, hb[e], lb[e]);
      c[e] = cc;
    }
    hw = pk4(hb[0], hb[1], hb[2], hb[3]);
    lw = pk4(lb[0], lb[1], lb[2], lb[3]);
  };

  // L0 tile (x via K=32 path folded with <<3)
  auto l0_one = [&](int mt, f32x4& c, unsigned& hw, unsigned& lw){
    long  Xh = *(const long*)(L + xrd + mt*512);
    long  Xl = *(const long*)(L + xrd + mt*512 + 2048);
    i32x4 Hh = *(const i32x4*)(L + rdA0 + mt*4096);
    i32x4 Hl = *(const i32x4*)(L + rdA0 + mt*4096 + O1L);
    i32x4 cA[4], cB[4];
    const i32x4 z = {0,0,0,0};
    #pragma unroll
    for (int g = 0; g < 4; ++g){
      i32x4 hA = MFMA64(Hh, WB0h[g][0], z);
      i32x4 hB = MFMA64(Hh, WB0h[g][1], z);
      hB = MFMA64(Hl, WB0h[g][0], hB);
      i32x4 xA = MFMA32(Xh, WB0x[g][0], z);
      i32x4 xB = MFMA32(Xh, WB0x[g][1], z);
      xB = MFMA32(Xl, WB0x[g][0], xB);
      #pragma unroll
      for (int e = 0; e < 4; ++e){
        cA[g][e] = hA[e] + (xA[e] << 3);
        cB[g][e] = hB[e] + (xB[e] << 3);
      }
    }
    int hb[4], lb[4];
    #pragma unroll
    for (int e = 0; e < 4; ++e){
      float t0 = fmaf(fmaf((float)cB[0][e], 0.0078125f, (float)cA[0][e]), kA0[0], kC0[0]);
      float t1 = fmaf(fmaf((float)cB[1][e], 0.0078125f, (float)cA[1][e]), kA0[1], kC0[1]);
      float t2 = fmaf(fmaf((float)cB[2][e], 0.0078125f, (float)cA[2][e]), kA0[2], kC0[2]);
      float t3 = fmaf(fmaf((float)cB[3][e], 0.0078125f, (float)cA[3][e]), kA0[3], kC0[3]);
      float cc = c[e];
      cellupd(t0, t1, t2, t3, cc, hb[e], lb[e]);
      c[e] = cc;
    }
    hw = pk4(hb[0], hb[1], hb[2], hb[3]);
    lw = pk4(lb[0], lb[1], lb[2], lb[3]);
  };

  // ---- pre-loop: L0(0) alone (h0(-1)=0 region is zeroed)
  {
    float4 xv; bool doX = tid < 192;
    if (doX) xv = *(const float4*)&x[((size_t)(rowBase + xr)*T + 1)*F + xq*4];
    unsigned h0w[2], h0l[2];
    l0_one(0, c0r[0], h0w[0], h0l[0]);
    l0_one(1, c0r[1], h0w[1], h0l[1]);
    __syncthreads();
    #pragma unroll
    for (int mt = 0; mt < 2; ++mt)
      #pragma unroll
      for (int e = 0; e < 4; ++e){
        L[stB[e] + mt*4096]       = (char)(h0w[mt] >> (8*e));
        L[stB[e] + mt*4096 + O1L] = (char)(h0l[mt] >> (8*e));
      }
    if (doX){
      unsigned lw, hw = quantw(xv, lw);
      *(unsigned*)(L + xst) = hw; *(unsigned*)(L + xst + 2048) = lw;
    }
    __syncthreads();
  }

  // ---- main fused loop: iteration i computes L1(i) and L0(i+1)
  for (int i = 0; i < T-1; ++i){
    float4 xv; const bool doX = (i < T-2) && (tid < 192);
    if (doX) xv = *(const float4*)&x[((size_t)(rowBase + xr)*T + (i+2))*F + xq*4];

    unsigned h1w[4], h1l[4], h0w[2], h0l[2];
    l1_one(0, c1r[0], h1w[0], h1l[0]);
    l1_one(1, c1r[1], h1w[1], h1l[1]);
    l0_one(0, c0r[0], h0w[0], h0l[0]);
    l1_one(2, c1r[2], h1w[2], h1l[2]);
    l0_one(1, c0r[1], h0w[1], h0l[1]);
    l1_one(3, c1r[3], h1w[3], h1l[3]);
    __syncthreads();

    #pragma unroll
    for (int mt = 0; mt < 4; ++mt)
      #pragma unroll
      for (int e = 0; e < 4; ++e){
        L[stA[e] + mt*4096]       = (char)(h1w[mt] >> (8*e));
        L[stA[e] + mt*4096 + O1L] = (char)(h1l[mt] >> (8*e));
      }
    #pragma unroll
    for (int mt = 0; mt < 2; ++mt)
      #pragma unroll
      for (int e = 0; e < 4; ++e){
        L[stB[e] + mt*4096]       = (char)(h0w[mt] >> (8*e));
        L[stB[e] + mt*4096 + O1L] = (char)(h0l[mt] >> (8*e));
      }
    if (doX){
      unsigned lw, hw = quantw(xv, lw);
      *(unsigned*)(L + xst) = hw; *(unsigned*)(L + xst + 2048) = lw;
    }
    __syncthreads();
  }

  // ---- final: L1(T-1)
  {
    unsigned h1w[4], h1l[4];
    l1_one(0, c1r[0], h1w[0], h1l[0]);
    l1_one(1, c1r[1], h1w[1], h1l[1]);
    l1_one(2, c1r[2], h1w[2], h1l[2]);
    l1_one(3, c1r[3], h1w[3], h1l[3]);
    __syncthreads();
    #pragma unroll
    for (int mt = 0; mt < 4; ++mt)
      #pragma unroll
      for (int e = 0; e < 4; ++e){
        L[stA[e] + mt*4096]       = (char)(h1w[mt] >> (8*e));
        L[stA[e] + mt*4096 + O1L] = (char)(h1l[mt] >> (8*e));
      }
    __syncthreads();
  }

  // ---- epilogue: pred = h1 . w_eff + b_eff
  {
    int r = tid >> 3, s = tid & 7;
    const float* wE = (const float*)(L + OWE);
    float sum = 0.f;
    #pragma unroll
    for (int cc = 0; cc < 16; ++cc){
      int c = s*16 + cc;
      int ad = r*256 + ((64 + c) ^ ((r & 7) << 4));
      float hq = 128.f*(float)(signed char)L[ad] + (float)(signed char)L[ad + O1L];
      sum += hq * HINV * wE[c];
    }
    sum += __shfl_down(sum, 4);
    sum += __shfl_down(sum, 2);
    sum += __shfl_down(sum, 1);
    if (s == 0) out[rowBase + r] = sum + wE[128];
  }
}

extern "C" void kernel_launch(void* const* d_in, const int* in_sizes, int n_in,
                              void* d_out, int out_size, void* d_ws, size_t ws_size,
                              hipStream_t stream) {
  const float* x    = (const float*)d_in[0];
  const float* cs   = (const float*)d_in[1];
  const float* fc1w = (const float*)d_in[2];
  const float* fc1b = (const float*)d_in[3];
  const float* fc2w = (const float*)d_in[4];
  const float* fc2b = (const float*)d_in[5];
  const float* b0i  = (const float*)d_in[8];
  const float* b0h  = (const float*)d_in[9];
  const float* w0i  = (const float*)d_in[6];
  const float* w0h  = (const float*)d_in[7];
  const float* w1i  = (const float*)d_in[10];
  const float* w1h  = (const float*)d_in[11];
  const float* b1i  = (const float*)d_in[12];
  const float* b1h  = (const float*)d_in[13];
  const float* d1w  = (const float*)d_in[14];
  const float* d1b  = (const float*)d_in[15];
  const float* d2w  = (const float*)d_in[16];
  const float* d2b  = (const float*)d_in[17];

  char* ws = (char*)d_ws;
  prequant<<<960, 64, 0, stream>>>(fc1w, fc2w, w0i, w0h, w1i, w1h, ws);

  const int Btot = in_sizes[0] / (T * F);   // 131072
  const int grid = Btot / R;                // 2048
  caurec<<<grid, 512, 0, stream>>>(x, cs, fc1b, fc2b, b0i, b0h, b1i, b1h,
                                   d1w, d1b, d2w, d2b, ws, (float*)d_out);
}

// Round 5
// 1273.079 us; speedup vs baseline: 1.8807x; 1.8807x over previous
//
#include <hip/hip_runtime.h>

// CauRecNet: 2-layer LSTM, B=131072 x T=15, i8-pair (14-bit fixed point) MFMA.
// Round 5: mega-fused phase {L1(t) + L0(t+1)}, double-buffered LDS state,
// immediate stores, 1 barrier/step, k-constants in LDS. Target: no spills
// (round 4 spilled: FETCH 5.9GB of scratch reloads).

typedef int   i32x4 __attribute__((ext_vector_type(4)));
typedef float f32x4 __attribute__((ext_vector_type(4)));

#define DEV static __device__ __forceinline__

DEV float fexp2(float x){ return __builtin_amdgcn_exp2f(x); }
DEV float frcp (float x){ return __builtin_amdgcn_rcpf(x); }

#define MFMA64(A,B,C) __builtin_amdgcn_mfma_i32_16x16x64_i8(A,B,C,0,0,0)
#define MFMA32(A,B,C) __builtin_amdgcn_mfma_i32_16x16x32_i8(A,B,C,0,0,0)

constexpr int T = 15, F = 12, CS = 96;
constexpr int R = 64;

// d_ws layout (bytes) — unchanged
constexpr int Q1OFF  = 0;
constexpr int Q0OFF  = 196608;
constexpr int QF2OFF = 245760;
constexpr int QF1OFF = 278528;
constexpr int S1OFF  = 294912;
constexpr int S0OFF  = 296960;
constexpr int SF2OFF = 297984;
constexpr int SF1OFF = 298496;

constexpr float QM   = 16128.0f;
constexpr float QMX  = 2016.0f;
constexpr float HINV = 1.0f/16128.0f;
constexpr float NL2E = -1.44269504f, PL2E2 = 2.88539008f;
constexpr float MAGIC = 12582912.0f;   // 1.5 * 2^23
constexpr int   MAGI  = 0x4B400000;

// LDS map (hi regions; lo mirror at +LOD for h0/h1/x)
constexpr int OH0 = 0;       // h0 hi: buf0 @0, buf1 @8192   (64 rows x 128B)
constexpr int OH1 = 16384;   // h1 hi: buf0 @16384, buf1 @24576
constexpr int OX  = 32768;   // x  hi: buf0 @32768, buf1 @34816 (64 x 32B)
constexpr int OKC = 36864;   // kconst: L1kA@+0, L1kC@+2048, L0kA@+4096, L0kC@+6144
constexpr int LOD = 45056;   // lo mirror delta
constexpr int OWE = 81920;   // wEff floats
constexpr int LDSB= 82560;

// ---------------- weight pre-quantization (unchanged) ----------------
__global__ __launch_bounds__(64) void prequant(
    const float* __restrict__ fc1w, const float* __restrict__ fc2w,
    const float* __restrict__ w0i,  const float* __restrict__ w0h,
    const float* __restrict__ w1i,  const float* __restrict__ w1h,
    char* __restrict__ ws)
{
  const int r = blockIdx.x, j = threadIdx.x;
  float v[3] = {0.f, 0.f, 0.f};
  int   kk[3] = {-1, -1, -1};
  int type, n;
  if (r < 512){ type = 0; n = r; }
  else if (r < 768){ type = 1; n = r - 512; }
  else if (r < 896){ type = 2; n = r - 768; }
  else { type = 3; n = r - 896; }

  if (type == 0){
    for (int c = 0; c < 3; ++c){
      int k = j + c*64; kk[c] = k;
      v[c] = (k < 64) ? w1i[n*64 + k] : w1h[n*128 + (k - 64)];
    }
  } else if (type == 1){
    kk[0] = j;
    v[0] = (j < 32) ? ((j < 12) ? w0i[n*12 + j] : 0.f) : w0h[n*64 + (j - 32)];
    if (j < 32){ kk[1] = 64 + j; v[1] = w0h[n*64 + (32 + j)]; }
  } else {
    const float* fw = (type == 2) ? fc2w : fc1w;
    for (int c = 0; c < 2; ++c){
      int k = j + c*64; kk[c] = k;
      v[c] = (k < 96) ? fw[n*CS + k] : 0.f;
    }
  }
  float m = fmaxf(fmaxf(fabsf(v[0]), fabsf(v[1])), fabsf(v[2]));
  #pragma unroll
  for (int d = 32; d; d >>= 1) m = fmaxf(m, __shfl_xor(m, d));
  float s   = (m > 0.f) ? (m / 16120.0f) : 1.0f;
  float inv = (m > 0.f) ? (16120.0f / m) : 0.0f;
  if (j == 0){
    float* sp = (float*)(ws + (type==0 ? S1OFF : type==1 ? S0OFF : type==2 ? SF2OFF : SF1OFF));
    sp[n] = s;
  }
  const int lr = n & 15;
  #pragma unroll
  for (int c = 0; c < 3; ++c){
    int k = kk[c];
    if (k < 0) continue;
    float q  = rintf(v[c] * inv);
    float hf = rintf(q * 0.0078125f);
    int hi = (int)hf, lo = (int)(q - hf*128.0f);
    long offh, offl;
    if (type == 0){
      int g = n >> 7, wv = (n & 127) >> 4;
      int ks = k >> 6, lg = (k >> 4) & 3, jj = k & 15, lane = lg*16 + lr;
      long base = Q1OFF + (((long)((wv*4+g)*3+ks)*2*64) + lane)*16 + jj;
      offh = base; offl = base + 1024;
    } else if (type == 1){
      int g = n >> 6, grp = (n & 63) >> 4;
      long b0 = Q0OFF + (long)(grp*4+g)*3072;
      if (k < 32){ int lg = (k>>3)&3, jj = k&7, lane = lg*16+lr;
        offh = b0 + lane*8 + jj; offl = offh + 512;
      } else { int kh = k-32, lg = kh>>4, jj = kh&15, lane = lg*16+lr;
        offh = b0 + 1024 + lane*16 + jj; offl = offh + 1024;
      }
    } else {
      int ks = k >> 6, lg = (k>>4)&3, jj = k&15, lane = lg*16+lr;
      int grp = n >> 4;
      long base = (type==2 ? QF2OFF : QF1OFF) + ((long)((grp*2+ks)*2)*64 + lane)*16 + jj;
      offh = base; offl = base + 1024;
    }
    ws[offh] = (char)hi; ws[offl] = (char)lo;
  }
}

// ---------------- helpers ----------------
DEV unsigned pk4(int b0, int b1, int b2, int b3){
  unsigned p01 = __builtin_amdgcn_perm((unsigned)b1, (unsigned)b0, 0x00000400u);
  unsigned p23 = __builtin_amdgcn_perm((unsigned)b3, (unsigned)b2, 0x04000000u);
  return __builtin_amdgcn_perm(p23, p01, 0x07060100u);
}

DEV void cellupd(float t0, float t1, float t2, float t3,
                 float& c, int& hi, int& lo){
  float gi = frcp(1.f + fexp2(t0));
  float gf = frcp(1.f + fexp2(t1));
  float gg = fmaf(-2.f, frcp(1.f + fexp2(t2)), 1.f);
  float go = frcp(1.f + fexp2(t3));
  float tmp = fmaf(gf, c, gi*gg);
  c += tmp;
  float th = fmaf(-2.f, frcp(1.f + fexp2(tmp*PL2E2)), 1.f);
  int qi = __float_as_int(fmaf(go*th, QM, MAGIC)) - MAGI;
  hi = (qi + 64) >> 7;
  lo = qi - (hi << 7);
}

DEV unsigned quantw(float4 v, unsigned& lw){
  int h[4], l[4];
  float vv[4] = {v.x, v.y, v.z, v.w};
  #pragma unroll
  for (int e = 0; e < 4; ++e){
    int qi = __float_as_int(fmaf(vv[e], QMX, MAGIC)) - MAGI;
    h[e] = (qi + 64) >> 7;
    l[e] = qi - (h[e] << 7);
  }
  lw = pk4(l[0], l[1], l[2], l[3]);
  return pk4(h[0], h[1], h[2], h[3]);
}

// ---------------- main recurrence kernel ----------------
__global__ __launch_bounds__(512, 2) void caurec(
    const float* __restrict__ x,    const float* __restrict__ cs,
    const float* __restrict__ fc1b, const float* __restrict__ fc2b,
    const float* __restrict__ b0i,  const float* __restrict__ b0h,
    const float* __restrict__ b1i,  const float* __restrict__ b1h,
    const float* __restrict__ d1w,  const float* __restrict__ d1b,
    const float* __restrict__ d2w,  const float* __restrict__ d2b,
    const char* __restrict__ ws,    float* __restrict__ out)
{
  __shared__ alignas(16) char L[LDSB];

  const int tid  = threadIdx.x;
  const int wave = tid >> 6, lane = tid & 63, lr = lane & 15, lg = lane >> 4;
  const int n0   = (wave & 3) * 16, mB0 = (wave >> 2) * 32, n1 = wave * 16;
  const int grp  = wave & 3;
  const int rowBase = blockIdx.x * R;
  const int sw8  = (lr & 7) << 4;

  // per-lane bases
  const int base0  = OH0 + lr*128 + ((lg*16) ^ sw8);   // h0 A-read (row lr; +mt*2048)
  const int base0w = base0 + mB0*128;                  // h0 A-read for l0 tiles
  const int base1  = OH1 + lr*128 + ((lg*16) ^ sw8);   // h1 ks1
  const int base1x = base1 ^ 64;                       // h1 ks2
  const int xrdb   = OX + (mB0 + lr)*32 + lg*8;
  const int kad1   = OKC + wave*256 + lr*16;
  const int cst1   = OH1 + (lg*4)*128 + ((n1 + lr) ^ ((lg & 1) << 6));
  const int cst0   = OH0 + (mB0 + lg*4)*128 + ((n0 + lr) ^ ((lg & 1) << 6));
  const int xr = tid/3, xq = tid - (tid/3)*3;
  const int xst = OX + xr*32 + xq*4;

  // ---- zero: h0 b1, h1 b0, x (hi) + lo mirrors
  {
    unsigned* W = (unsigned*)L;
    for (int i = tid; i < 4096; i += 512) W[2048  + i] = 0u;  // [8192,24576)
    for (int i = tid; i < 1024; i += 512) W[8192  + i] = 0u;  // [32768,36864)
    for (int i = tid; i < 4096; i += 512) W[13312 + i] = 0u;  // [53248,69632)
    for (int i = tid; i < 1024; i += 512) W[19456 + i] = 0u;  // [77824,81920)
  }
  __syncthreads();

  // ---- stage cs -> h1 buf1 (full 128 cols, zeros beyond 96); x(0); wEff; kconst
  {
    int r = tid >> 3, cg = (tid & 7) * 16;
    float vv[16];
    #pragma unroll
    for (int u = 0; u < 4; ++u){
      if (cg + u*4 < CS){
        float4 v = *(const float4*)&cs[(size_t)(rowBase + r)*CS + cg + u*4];
        vv[u*4] = v.x; vv[u*4+1] = v.y; vv[u*4+2] = v.z; vv[u*4+3] = v.w;
      } else { vv[u*4] = vv[u*4+1] = vv[u*4+2] = vv[u*4+3] = 0.f; }
    }
    i32x4 HV, LV;
    #pragma unroll
    for (int u = 0; u < 4; ++u){
      unsigned lw, hw = quantw(make_float4(vv[u*4], vv[u*4+1], vv[u*4+2], vv[u*4+3]), lw);
      HV[u] = (int)hw; LV[u] = (int)lw;
    }
    char* pcs = L + OH1 + 8192 + r*128 + (cg ^ ((r & 7) << 4));
    *(i32x4*)pcs = HV;
    *(i32x4*)(pcs + LOD) = LV;
  }
  if (tid < 192){
    float4 v = *(const float4*)&x[((size_t)(rowBase + xr)*T + 0)*F + xq*4];
    unsigned lw, hw = quantw(v, lw);
    char* pw = L + xst;                       // x(0) -> buf0
    *(unsigned*)pw = hw; *(unsigned*)(pw + LOD) = lw;
  }
  if (tid < 128){
    float s = 0.f;
    for (int a = 0; a < 64; ++a) s += d2w[a] * d1w[a*128 + tid];
    ((float*)(L + OWE))[tid] = s;
  } else if (tid == 128){
    float s = 0.f;
    for (int a = 0; a < 64; ++a) s += d2w[a] * d1b[a];
    ((float*)(L + OWE))[128] = s + d2b[0];
  }
  if (lg == 0){
    const float* S1p = (const float*)(ws + S1OFF);
    const float* S0p = (const float*)(ws + S0OFF);
    f32x4 a1, c1k, a0, c0k;
    #pragma unroll
    for (int g = 0; g < 4; ++g){
      float f = (g == 2) ? PL2E2 : NL2E;
      a1[g]  = f * 16384.f * (S1p[g*128 + n1 + lr] * HINV);
      c1k[g] = f * (b1i[g*128 + n1 + lr] + b1h[g*128 + n1 + lr]);
      a0[g]  = f * 16384.f * (S0p[g*64 + n0 + lr] * HINV);
      c0k[g] = f * (b0i[g*64 + n0 + lr] + b0h[g*64 + n0 + lr]);
    }
    char* pk = L + kad1;
    *(f32x4*)pk          = a1;
    *(f32x4*)(pk + 2048) = c1k;
    *(f32x4*)(pk + 4096) = a0;
    *(f32x4*)(pk + 6144) = c0k;
  }

  // persistent weight fragments (global loads; no LDS dep)
  i32x4 WB1[4][3][2];
  #pragma unroll
  for (int g = 0; g < 4; ++g)
    #pragma unroll
    for (int ks = 0; ks < 3; ++ks)
      #pragma unroll
      for (int sp = 0; sp < 2; ++sp)
        WB1[g][ks][sp] = *(const i32x4*)(ws + Q1OFF + ((long)(((wave*4+g)*3+ks)*2+sp)*64 + lane)*16);
  i32x4 WB0h[4][2]; long WB0x[4][2];
  #pragma unroll
  for (int g = 0; g < 4; ++g){
    const char* b0p = ws + Q0OFF + (long)(grp*4+g)*3072;
    #pragma unroll
    for (int sp = 0; sp < 2; ++sp){
      WB0x[g][sp] = *(const long*)(b0p + sp*512 + lane*8);
      WB0h[g][sp] = *(const i32x4*)(b0p + 1024 + sp*1024 + lane*16);
    }
  }
  __syncthreads();

  // ---- init GEMMs from cs staged in h1 buf1
  f32x4 c1r[4], c0r[2];
  {
    float sf2 = ((const float*)(ws + SF2OFF))[n1 + lr] * (HINV * 8.0f);
    float bb2 = fc2b[n1 + lr];
    #pragma unroll
    for (int mt = 0; mt < 4; ++mt){
      i32x4 aA = {0,0,0,0}, aB = {0,0,0,0};
      const char* p0 = L + base1  + 8192 + mt*2048;
      const char* p1 = L + base1x + 8192 + mt*2048;
      #pragma unroll
      for (int ks = 0; ks < 2; ++ks){
        const char* pp = ks ? p1 : p0;
        i32x4 Ah = *(const i32x4*)pp;
        i32x4 Al = *(const i32x4*)(pp + LOD);
        i32x4 Bh = *(const i32x4*)(ws + QF2OFF + ((long)((wave*2+ks)*2+0)*64 + lane)*16);
        i32x4 Bl = *(const i32x4*)(ws + QF2OFF + ((long)((wave*2+ks)*2+1)*64 + lane)*16);
        aA = MFMA64(Ah, Bh, aA); aB = MFMA64(Ah, Bl, aB); aB = MFMA64(Al, Bh, aB);
      }
      #pragma unroll
      for (int e = 0; e < 4; ++e)
        c1r[mt][e] = (16384.f*(float)aA[e] + 128.f*(float)aB[e])*sf2 + bb2;
    }
    float sf1 = ((const float*)(ws + SF1OFF))[n0 + lr] * (HINV * 8.0f);
    float bb1 = fc1b[n0 + lr];
    #pragma unroll
    for (int mt = 0; mt < 2; ++mt){
      i32x4 aA = {0,0,0,0}, aB = {0,0,0,0};
      const char* p0 = L + base1  + 8192 + mB0*128 + mt*2048;
      const char* p1 = L + base1x + 8192 + mB0*128 + mt*2048;
      #pragma unroll
      for (int ks = 0; ks < 2; ++ks){
        const char* pp = ks ? p1 : p0;
        i32x4 Ah = *(const i32x4*)pp;
        i32x4 Al = *(const i32x4*)(pp + LOD);
        i32x4 Bh = *(const i32x4*)(ws + QF1OFF + ((long)((grp*2+ks)*2+0)*64 + lane)*16);
        i32x4 Bl = *(const i32x4*)(ws + QF1OFF + ((long)((grp*2+ks)*2+1)*64 + lane)*16);
        aA = MFMA64(Ah, Bh, aA); aB = MFMA64(Ah, Bl, aB); aB = MFMA64(Al, Bh, aB);
      }
      #pragma unroll
      for (int e = 0; e < 4; ++e)
        c0r[mt][e] = (16384.f*(float)aA[e] + 128.f*(float)aB[e])*sf1 + bb1;
    }
  }

  // ---- tile lambdas (pofs = read-buf offset, qofs = write-buf offset)
  auto l1_one = [&](int mt, int pofs, int qofs){
    i32x4 aA[4], aB[4];
    #pragma unroll
    for (int g = 0; g < 4; ++g){ aA[g] = i32x4{0,0,0,0}; aB[g] = i32x4{0,0,0,0}; }
    {
      const char* pp = L + base0 + pofs + mt*2048;     // ks0: h0
      i32x4 Hh = *(const i32x4*)pp, Hl = *(const i32x4*)(pp + LOD);
      #pragma unroll
      for (int g = 0; g < 4; ++g){
        aA[g] = MFMA64(Hh, WB1[g][0][0], aA[g]);
        aB[g] = MFMA64(Hh, WB1[g][0][1], aB[g]);
        aB[g] = MFMA64(Hl, WB1[g][0][0], aB[g]);
      }
    }
    {
      const char* pp = L + base1 + pofs + mt*2048;     // ks1: h1 cols [0,64)
      i32x4 Hh = *(const i32x4*)pp, Hl = *(const i32x4*)(pp + LOD);
      #pragma unroll
      for (int g = 0; g < 4; ++g){
        aA[g] = MFMA64(Hh, WB1[g][1][0], aA[g]);
        aB[g] = MFMA64(Hh, WB1[g][1][1], aB[g]);
        aB[g] = MFMA64(Hl, WB1[g][1][0], aB[g]);
      }
    }
    {
      const char* pp = L + base1x + pofs + mt*2048;    // ks2: h1 cols [64,128)
      i32x4 Hh = *(const i32x4*)pp, Hl = *(const i32x4*)(pp + LOD);
      #pragma unroll
      for (int g = 0; g < 4; ++g){
        aA[g] = MFMA64(Hh, WB1[g][2][0], aA[g]);
        aB[g] = MFMA64(Hh, WB1[g][2][1], aB[g]);
        aB[g] = MFMA64(Hl, WB1[g][2][0], aB[g]);
      }
    }
    f32x4 kA = *(const f32x4*)(L + kad1);
    f32x4 kC = *(const f32x4*)(L + kad1 + 2048);
    int hb[4], lb[4];
    #pragma unroll
    for (int e = 0; e < 4; ++e){
      float t0 = fmaf(fmaf((float)aB[0][e], 0.0078125f, (float)aA[0][e]), kA[0], kC[0]);
      float t1 = fmaf(fmaf((float)aB[1][e], 0.0078125f, (float)aA[1][e]), kA[1], kC[1]);
      float t2 = fmaf(fmaf((float)aB[2][e], 0.0078125f, (float)aA[2][e]), kA[2], kC[2]);
      float t3 = fmaf(fmaf((float)aB[3][e], 0.0078125f, (float)aA[3][e]), kA[3], kC[3]);
      float cc = c1r[mt][e];
      cellupd(t0, t1, t2, t3, cc, hb[e], lb[e]);
      c1r[mt][e] = cc;
    }
    unsigned hw = pk4(hb[0], hb[1], hb[2], hb[3]);
    unsigned lw = pk4(lb[0], lb[1], lb[2], lb[3]);
    const int sb = cst1 + qofs + mt*2048;
    #pragma unroll
    for (int e = 0; e < 4; ++e){
      char* pa = L + (sb ^ (e << 4));
      pa[e*128]       = (char)(hw >> (8*e));
      pa[e*128 + LOD] = (char)(lw >> (8*e));
    }
  };

  auto l0_one = [&](int mt, int pofs, int xofs, int qofs){
    const char* px = L + xrdb + xofs + mt*512;
    long Xh = *(const long*)px, Xl = *(const long*)(px + LOD);
    const char* ph = L + base0w + pofs + mt*2048;
    i32x4 Hh = *(const i32x4*)ph, Hl = *(const i32x4*)(ph + LOD);
    i32x4 cA[4], cB[4];
    const i32x4 z = {0,0,0,0};
    #pragma unroll
    for (int g = 0; g < 4; ++g){
      i32x4 hA = MFMA64(Hh, WB0h[g][0], z);
      i32x4 hB = MFMA64(Hh, WB0h[g][1], z);
      hB = MFMA64(Hl, WB0h[g][0], hB);
      i32x4 xA = MFMA32(Xh, WB0x[g][0], z);
      i32x4 xB = MFMA32(Xh, WB0x[g][1], z);
      xB = MFMA32(Xl, WB0x[g][0], xB);
      #pragma unroll
      for (int e = 0; e < 4; ++e){
        cA[g][e] = hA[e] + (xA[e] << 3);
        cB[g][e] = hB[e] + (xB[e] << 3);
      }
    }
    f32x4 kA = *(const f32x4*)(L + kad1 + 4096);
    f32x4 kC = *(const f32x4*)(L + kad1 + 6144);
    int hb[4], lb[4];
    #pragma unroll
    for (int e = 0; e < 4; ++e){
      float t0 = fmaf(fmaf((float)cB[0][e], 0.0078125f, (float)cA[0][e]), kA[0], kC[0]);
      float t1 = fmaf(fmaf((float)cB[1][e], 0.0078125f, (float)cA[1][e]), kA[1], kC[1]);
      float t2 = fmaf(fmaf((float)cB[2][e], 0.0078125f, (float)cA[2][e]), kA[2], kC[2]);
      float t3 = fmaf(fmaf((float)cB[3][e], 0.0078125f, (float)cA[3][e]), kA[3], kC[3]);
      float cc = c0r[mt][e];
      cellupd(t0, t1, t2, t3, cc, hb[e], lb[e]);
      c0r[mt][e] = cc;
    }
    unsigned hw = pk4(hb[0], hb[1], hb[2], hb[3]);
    unsigned lw = pk4(lb[0], lb[1], lb[2], lb[3]);
    const int sb = cst0 + qofs + mt*2048;
    #pragma unroll
    for (int e = 0; e < 4; ++e){
      char* pa = L + (sb ^ (e << 4));
      pa[e*128]       = (char)(hw >> (8*e));
      pa[e*128 + LOD] = (char)(lw >> (8*e));
    }
  };

  // ---- pre-loop: L0(0) (reads h0(-1)=zeros buf1, x(0) buf0) -> h0(0) buf0; stage x(1)->buf1
  {
    float4 xv; const bool doX = tid < 192;
    if (doX) xv = *(const float4*)&x[((size_t)(rowBase + xr)*T + 1)*F + xq*4];
    l0_one(0, 8192, 0, 0);
    l0_one(1, 8192, 0, 0);
    if (doX){
      unsigned lw, hw = quantw(xv, lw);
      char* pw = L + xst + 2048;
      *(unsigned*)pw = hw; *(unsigned*)(pw + LOD) = lw;
    }
    __syncthreads();
  }

  // ---- main loop: M(i) computes L1(i) + L0(i+1); 1 barrier per step
  for (int j = 0; j < 7; ++j){
    { // M(2j): p=0 -> reads buf0 (h0,h1), x buf1; writes buf1; stage x(2j+2)->buf0
      float4 xv; const bool doX = tid < 192;
      if (doX) xv = *(const float4*)&x[((size_t)(rowBase + xr)*T + (2*j + 2))*F + xq*4];
      l1_one(0, 0, 8192);
      l1_one(1, 0, 8192);
      l0_one(0, 0, 2048, 8192);
      l1_one(2, 0, 8192);
      l0_one(1, 0, 2048, 8192);
      l1_one(3, 0, 8192);
      if (doX){
        unsigned lw, hw = quantw(xv, lw);
        char* pw = L + xst;
        *(unsigned*)pw = hw; *(unsigned*)(pw + LOD) = lw;
      }
      __syncthreads();
    }
    { // M(2j+1): p=1 -> reads buf1, x buf0; writes buf0; stage x(2j+3)->buf1 (j<6)
      float4 xv; const bool doX = (j < 6) && (tid < 192);
      if (doX) xv = *(const float4*)&x[((size_t)(rowBase + xr)*T + (2*j + 3))*F + xq*4];
      l1_one(0, 8192, 0);
      l1_one(1, 8192, 0);
      l0_one(0, 8192, 0, 0);
      l1_one(2, 8192, 0);
      l0_one(1, 8192, 0, 0);
      l1_one(3, 8192, 0);
      if (doX){
        unsigned lw, hw = quantw(xv, lw);
        char* pw = L + xst + 2048;
        *(unsigned*)pw = hw; *(unsigned*)(pw + LOD) = lw;
      }
      __syncthreads();
    }
  }

  // ---- final: L1(14) (p=0) -> h1(15) into buf1
  {
    l1_one(0, 0, 8192);
    l1_one(1, 0, 8192);
    l1_one(2, 0, 8192);
    l1_one(3, 0, 8192);
    __syncthreads();
  }

  // ---- epilogue: pred = h1 . w_eff + b_eff (h1 in buf1)
  {
    int r = tid >> 3, s = tid & 7;
    const float* wE = (const float*)(L + OWE);
    float sum = 0.f;
    #pragma unroll
    for (int cc = 0; cc < 16; ++cc){
      int c = s*16 + cc;
      const char* pe = L + OH1 + 8192 + r*128 + (c ^ ((r & 7) << 4));
      float hq = 128.f*(float)(signed char)pe[0] + (float)(signed char)pe[LOD];
      sum += hq * HINV * wE[c];
    }
    sum += __shfl_down(sum, 4);
    sum += __shfl_down(sum, 2);
    sum += __shfl_down(sum, 1);
    if (s == 0) out[rowBase + r] = sum + wE[128];
  }
}

extern "C" void kernel_launch(void* const* d_in, const int* in_sizes, int n_in,
                              void* d_out, int out_size, void* d_ws, size_t ws_size,
                              hipStream_t stream) {
  const float* x    = (const float*)d_in[0];
  const float* cs   = (const float*)d_in[1];
  const float* fc1w = (const float*)d_in[2];
  const float* fc1b = (const float*)d_in[3];
  const float* fc2w = (const float*)d_in[4];
  const float* fc2b = (const float*)d_in[5];
  const float* w0i  = (const float*)d_in[6];
  const float* w0h  = (const float*)d_in[7];
  const float* b0i  = (const float*)d_in[8];
  const float* b0h  = (const float*)d_in[9];
  const float* w1i  = (const float*)d_in[10];
  const float* w1h  = (const float*)d_in[11];
  const float* b1i  = (const float*)d_in[12];
  const float* b1h  = (const float*)d_in[13];
  const float* d1w  = (const float*)d_in[14];
  const float* d1b  = (const float*)d_in[15];
  const float* d2w  = (const float*)d_in[16];
  const float* d2b  = (const float*)d_in[17];

  char* ws = (char*)d_ws;
  prequant<<<960, 64, 0, stream>>>(fc1w, fc2w, w0i, w0h, w1i, w1h, ws);

  const int Btot = in_sizes[0] / (T * F);   // 131072
  const int grid = Btot / R;                // 2048
  caurec<<<grid, 512, 0, stream>>>(x, cs, fc1b, fc2b, b0i, b0h, b1i, b1h,
                                   d1w, d1b, d2w, d2b, ws, (float*)d_out);
}

// Round 7
// 937.537 us; speedup vs baseline: 2.5538x; 1.3579x over previous
//
#include <hip/hip_runtime.h>

// CauRecNet: 2-layer LSTM, B=131072 x T=15, i8-pair (14-bit fixed point) MFMA.
// Round 7: round-6 + overflow clamp in cellupd (tmp<=12 before exp2; round 6's
// shared-rcp form produced inf*0=NaN for |c|~100s).

typedef int   i32x4 __attribute__((ext_vector_type(4)));
typedef float f32x4 __attribute__((ext_vector_type(4)));

#define DEV static __device__ __forceinline__

DEV float fexp2(float x){ return __builtin_amdgcn_exp2f(x); }
DEV float frcp (float x){ return __builtin_amdgcn_rcpf(x); }

#define MFMA64(A,B,C) __builtin_amdgcn_mfma_i32_16x16x64_i8(A,B,C,0,0,0)
#define MFMA32(A,B,C) __builtin_amdgcn_mfma_i32_16x16x32_i8(A,B,C,0,0,0)

constexpr int T = 15, F = 12, CS = 96;
constexpr int R = 64;

// d_ws layout (bytes) — unchanged
constexpr int Q1OFF  = 0;
constexpr int Q0OFF  = 196608;
constexpr int QF2OFF = 245760;
constexpr int QF1OFF = 278528;
constexpr int S1OFF  = 294912;
constexpr int S0OFF  = 296960;
constexpr int SF2OFF = 297984;
constexpr int SF1OFF = 298496;

constexpr float QM   = 16128.0f;
constexpr float QMX  = 2016.0f;
constexpr float HINV = 1.0f/16128.0f;
constexpr float NL2E = -1.44269504f, PL2E2 = 2.88539008f;
constexpr float MAGIC = 12582912.0f;   // 1.5 * 2^23
constexpr int   MAGI  = 0x4B400000;

// LDS map (hi regions; lo mirror at +LOD for h0/h1/x)
constexpr int OH0 = 0;       // h0 hi: buf0 @0, buf1 @8192   (64 rows x 128B)
constexpr int OH1 = 16384;   // h1 hi: buf0 @16384, buf1 @24576
constexpr int OX  = 32768;   // x  hi: buf0 @32768, buf1 @34816 (64 x 32B)
constexpr int OKC = 36864;   // kconst: L1kA@+0, L1kC@+2048, L0kA@+4096, L0kC@+6144
constexpr int LOD = 45056;   // lo mirror delta
constexpr int OWE = 81920;   // wEff floats (129)
constexpr int OWX = 82944;   // W0 x-fragments [16 chunks][1024B] = 16384
constexpr int OC  = 99328;   // c-states: [24 slots][512 thr][f32] = 49152
constexpr int LDSB= 148480;

// ---------------- weight pre-quantization (unchanged) ----------------
__global__ __launch_bounds__(64) void prequant(
    const float* __restrict__ fc1w, const float* __restrict__ fc2w,
    const float* __restrict__ w0i,  const float* __restrict__ w0h,
    const float* __restrict__ w1i,  const float* __restrict__ w1h,
    char* __restrict__ ws)
{
  const int r = blockIdx.x, j = threadIdx.x;
  float v[3] = {0.f, 0.f, 0.f};
  int   kk[3] = {-1, -1, -1};
  int type, n;
  if (r < 512){ type = 0; n = r; }
  else if (r < 768){ type = 1; n = r - 512; }
  else if (r < 896){ type = 2; n = r - 768; }
  else { type = 3; n = r - 896; }

  if (type == 0){
    for (int c = 0; c < 3; ++c){
      int k = j + c*64; kk[c] = k;
      v[c] = (k < 64) ? w1i[n*64 + k] : w1h[n*128 + (k - 64)];
    }
  } else if (type == 1){
    kk[0] = j;
    v[0] = (j < 32) ? ((j < 12) ? w0i[n*12 + j] : 0.f) : w0h[n*64 + (j - 32)];
    if (j < 32){ kk[1] = 64 + j; v[1] = w0h[n*64 + (32 + j)]; }
  } else {
    const float* fw = (type == 2) ? fc2w : fc1w;
    for (int c = 0; c < 2; ++c){
      int k = j + c*64; kk[c] = k;
      v[c] = (k < 96) ? fw[n*CS + k] : 0.f;
    }
  }
  float m = fmaxf(fmaxf(fabsf(v[0]), fabsf(v[1])), fabsf(v[2]));
  #pragma unroll
  for (int d = 32; d; d >>= 1) m = fmaxf(m, __shfl_xor(m, d));
  float s   = (m > 0.f) ? (m / 16120.0f) : 1.0f;
  float inv = (m > 0.f) ? (16120.0f / m) : 0.0f;
  if (j == 0){
    float* sp = (float*)(ws + (type==0 ? S1OFF : type==1 ? S0OFF : type==2 ? SF2OFF : SF1OFF));
    sp[n] = s;
  }
  const int lr = n & 15;
  #pragma unroll
  for (int c = 0; c < 3; ++c){
    int k = kk[c];
    if (k < 0) continue;
    float q  = rintf(v[c] * inv);
    float hf = rintf(q * 0.0078125f);
    int hi = (int)hf, lo = (int)(q - hf*128.0f);
    long offh, offl;
    if (type == 0){
      int g = n >> 7, wv = (n & 127) >> 4;
      int ks = k >> 6, lg = (k >> 4) & 3, jj = k & 15, lane = lg*16 + lr;
      long base = Q1OFF + (((long)((wv*4+g)*3+ks)*2*64) + lane)*16 + jj;
      offh = base; offl = base + 1024;
    } else if (type == 1){
      int g = n >> 6, grp = (n & 63) >> 4;
      long b0 = Q0OFF + (long)(grp*4+g)*3072;
      if (k < 32){ int lg = (k>>3)&3, jj = k&7, lane = lg*16+lr;
        offh = b0 + lane*8 + jj; offl = offh + 512;
      } else { int kh = k-32, lg = kh>>4, jj = kh&15, lane = lg*16+lr;
        offh = b0 + 1024 + lane*16 + jj; offl = offh + 1024;
      }
    } else {
      int ks = k >> 6, lg = (k>>4)&3, jj = k&15, lane = lg*16+lr;
      int grp = n >> 4;
      long base = (type==2 ? QF2OFF : QF1OFF) + ((long)((grp*2+ks)*2)*64 + lane)*16 + jj;
      offh = base; offl = base + 1024;
    }
    ws[offh] = (char)hi; ws[offl] = (char)lo;
  }
}

// ---------------- helpers ----------------
DEV unsigned pk4(int b0, int b1, int b2, int b3){
  unsigned p01 = __builtin_amdgcn_perm((unsigned)b1, (unsigned)b0, 0x00000400u);
  unsigned p23 = __builtin_amdgcn_perm((unsigned)b3, (unsigned)b2, 0x04000000u);
  return __builtin_amdgcn_perm(p23, p01, 0x07060100u);
}

// 8-trans cellupd, overflow-safe: tmp clamped to <=12 before exp2
// (tanh(12)=1-2e-11; unclamped |c|~1e2-1e3 made ec=inf -> inf*0=NaN).
DEV void cellupd(float t0, float t1, float t2, float t3,
                 float& c, int& hi, int& lo){
  float ei = fexp2(t0);                 // e^{-a_i}
  float ef = fexp2(t1);                 // e^{-a_f}
  float eg = fexp2(t2);                 // e^{2 a_g}
  float eo = fexp2(t3);                 // e^{-a_o}
  float r1 = frcp((1.f + ei) * (eg + 1.f));
  float ig = (eg - 1.f) * r1;           // sigmoid(i)*tanh(g)
  float gf = frcp(1.f + ef);            // sigmoid(f)
  float tmp = fmaf(c, gf, ig);          // f*c + i*g
  c += tmp;
  float tc = fminf(tmp, 12.0f);         // overflow clamp (pos side only)
  float ec = fexp2(tc * PL2E2);
  float r3 = frcp((1.f + eo) * (ec + 1.f));
  float h  = (ec - 1.f) * r3;           // sigmoid(o)*tanh(tmp)
  int qi = __float_as_int(fmaf(h, QM, MAGIC)) - MAGI;
  hi = (qi + 64) >> 7;
  lo = qi - (hi << 7);
}

DEV unsigned quantw(float4 v, unsigned& lw){
  int h[4], l[4];
  float vv[4] = {v.x, v.y, v.z, v.w};
  #pragma unroll
  for (int e = 0; e < 4; ++e){
    int qi = __float_as_int(fmaf(vv[e], QMX, MAGIC)) - MAGI;
    h[e] = (qi + 64) >> 7;
    l[e] = qi - (h[e] << 7);
  }
  lw = pk4(l[0], l[1], l[2], l[3]);
  return pk4(h[0], h[1], h[2], h[3]);
}

// ---------------- main recurrence kernel ----------------
__global__ __launch_bounds__(512, 2) void caurec(
    const float* __restrict__ x,    const float* __restrict__ cs,
    const float* __restrict__ fc1b, const float* __restrict__ fc2b,
    const float* __restrict__ b0i,  const float* __restrict__ b0h,
    const float* __restrict__ b1i,  const float* __restrict__ b1h,
    const float* __restrict__ d1w,  const float* __restrict__ d1b,
    const float* __restrict__ d2w,  const float* __restrict__ d2b,
    const char* __restrict__ ws,    float* __restrict__ out)
{
  __shared__ alignas(16) char L[LDSB];

  const int tid  = threadIdx.x;
  const int wave = tid >> 6, lane = tid & 63, lr = lane & 15, lg = lane >> 4;
  const int n0   = (wave & 3) * 16, mB0 = (wave >> 2) * 32, n1 = wave * 16;
  const int grp  = wave & 3;
  const int rowBase = blockIdx.x * R;
  const int sw8  = (lr & 7) << 4;

  // per-lane bases
  const int base0  = OH0 + lr*128 + ((lg*16) ^ sw8);   // h0 A-read (+mt*2048, +pofs)
  const int base0w = base0 + mB0*128;                  // h0 A-read for l0 tiles
  const int base1  = OH1 + lr*128 + ((lg*16) ^ sw8);   // h1 ks1
  const int base1x = base1 ^ 64;                       // h1 ks2
  const int xrdb   = OX + (mB0 + lr)*32 + lg*8;
  const int kad1   = OKC + wave*256 + lr*16;
  const int cst1   = OH1 + (lg*4)*128 + ((n1 + lr) ^ ((lg & 1) << 6));
  const int cst0   = OH0 + (mB0 + lg*4)*128 + ((n0 + lr) ^ ((lg & 1) << 6));
  const int owxb   = OWX + grp*4096 + lane*8;
  const int cbase  = OC + tid*4;
  const int xr = tid/3, xq = tid - (tid/3)*3;
  const int xst = OX + xr*32 + xq*4;

  // ---- zero: h0 b1 + h1 b0 (hi), x (hi), and lo mirrors
  {
    unsigned* W = (unsigned*)L;
    for (int i = tid; i < 4096; i += 512) W[2048  + i] = 0u;  // [8192,24576)
    for (int i = tid; i < 1024; i += 512) W[8192  + i] = 0u;  // [32768,36864)
    for (int i = tid; i < 4096; i += 512) W[13312 + i] = 0u;  // [53248,69632)
    for (int i = tid; i < 1024; i += 512) W[19456 + i] = 0u;  // [77824,81920)
  }
  __syncthreads();

  // ---- stage: cs -> h1 buf1; x(0) -> x buf0; wEff; kconst; W0x -> LDS
  {
    int r = tid >> 3, cg = (tid & 7) * 16;
    float vv[16];
    #pragma unroll
    for (int u = 0; u < 4; ++u){
      if (cg + u*4 < CS){
        float4 v = *(const float4*)&cs[(size_t)(rowBase + r)*CS + cg + u*4];
        vv[u*4] = v.x; vv[u*4+1] = v.y; vv[u*4+2] = v.z; vv[u*4+3] = v.w;
      } else { vv[u*4] = vv[u*4+1] = vv[u*4+2] = vv[u*4+3] = 0.f; }
    }
    i32x4 HV, LV;
    #pragma unroll
    for (int u = 0; u < 4; ++u){
      unsigned lw, hw = quantw(make_float4(vv[u*4], vv[u*4+1], vv[u*4+2], vv[u*4+3]), lw);
      HV[u] = (int)hw; LV[u] = (int)lw;
    }
    char* pcs = L + OH1 + 8192 + r*128 + (cg ^ ((r & 7) << 4));
    *(i32x4*)pcs = HV;
    *(i32x4*)(pcs + LOD) = LV;
  }
  if (tid < 192){
    float4 v = *(const float4*)&x[((size_t)(rowBase + xr)*T + 0)*F + xq*4];
    unsigned lw, hw = quantw(v, lw);
    char* pw = L + xst;                       // x(0) -> buf0
    *(unsigned*)pw = hw; *(unsigned*)(pw + LOD) = lw;
  }
  if (tid < 128){
    float s = 0.f;
    for (int a = 0; a < 64; ++a) s += d2w[a] * d1w[a*128 + tid];
    ((float*)(L + OWE))[tid] = s;
  } else if (tid == 128){
    float s = 0.f;
    for (int a = 0; a < 64; ++a) s += d2w[a] * d1b[a];
    ((float*)(L + OWE))[128] = s + d2b[0];
  }
  if (lg == 0){
    const float* S1p = (const float*)(ws + S1OFF);
    const float* S0p = (const float*)(ws + S0OFF);
    f32x4 a1, c1k, a0, c0k;
    #pragma unroll
    for (int g = 0; g < 4; ++g){
      float f = (g == 2) ? PL2E2 : NL2E;
      a1[g]  = f * 16384.f * (S1p[g*128 + n1 + lr] * HINV);
      c1k[g] = f * (b1i[g*128 + n1 + lr] + b1h[g*128 + n1 + lr]);
      a0[g]  = f * 16384.f * (S0p[g*64 + n0 + lr] * HINV);
      c0k[g] = f * (b0i[g*64 + n0 + lr] + b0h[g*64 + n0 + lr]);
    }
    char* pk = L + kad1;
    *(f32x4*)pk          = a1;
    *(f32x4*)(pk + 2048) = c1k;
    *(f32x4*)(pk + 4096) = a0;
    *(f32x4*)(pk + 6144) = c0k;
  }
  // W0 x-fragments -> LDS (16 chunks x 1024B, mirror of ws layout)
  #pragma unroll
  for (int k = 0; k < 4; ++k){
    int i = tid + k*512;
    int c16 = i >> 7, rem = i & 127;
    *(long*)(L + OWX + c16*1024 + rem*8) =
        *(const long*)(ws + Q0OFF + (long)c16*3072 + rem*8);
  }

  // persistent weight fragments (global loads; no LDS dep)
  i32x4 WB1[4][3][2];
  #pragma unroll
  for (int g = 0; g < 4; ++g)
    #pragma unroll
    for (int ks = 0; ks < 3; ++ks)
      #pragma unroll
      for (int sp = 0; sp < 2; ++sp)
        WB1[g][ks][sp] = *(const i32x4*)(ws + Q1OFF + ((long)(((wave*4+g)*3+ks)*2+sp)*64 + lane)*16);
  i32x4 WB0h[4][2];
  #pragma unroll
  for (int g = 0; g < 4; ++g){
    const char* b0p = ws + Q0OFF + (long)(grp*4+g)*3072;
    #pragma unroll
    for (int sp = 0; sp < 2; ++sp)
      WB0h[g][sp] = *(const i32x4*)(b0p + 1024 + sp*1024 + lane*16);
  }
  __syncthreads();

  // ---- init GEMMs from cs staged in h1 buf1 -> c states into LDS
  {
    float sf2 = ((const float*)(ws + SF2OFF))[n1 + lr] * (HINV * 8.0f);
    float bb2 = fc2b[n1 + lr];
    #pragma unroll
    for (int mt = 0; mt < 4; ++mt){
      i32x4 aA = {0,0,0,0}, aB = {0,0,0,0};
      const char* p0 = L + base1  + 8192 + mt*2048;
      const char* p1 = L + base1x + 8192 + mt*2048;
      #pragma unroll
      for (int ks = 0; ks < 2; ++ks){
        const char* pp = ks ? p1 : p0;
        i32x4 Ah = *(const i32x4*)pp;
        i32x4 Al = *(const i32x4*)(pp + LOD);
        i32x4 Bh = *(const i32x4*)(ws + QF2OFF + ((long)((wave*2+ks)*2+0)*64 + lane)*16);
        i32x4 Bl = *(const i32x4*)(ws + QF2OFF + ((long)((wave*2+ks)*2+1)*64 + lane)*16);
        aA = MFMA64(Ah, Bh, aA); aB = MFMA64(Ah, Bl, aB); aB = MFMA64(Al, Bh, aB);
      }
      #pragma unroll
      for (int e = 0; e < 4; ++e)
        *(float*)(L + cbase + (mt*4 + e)*2048) =
            (16384.f*(float)aA[e] + 128.f*(float)aB[e])*sf2 + bb2;
    }
    float sf1 = ((const float*)(ws + SF1OFF))[n0 + lr] * (HINV * 8.0f);
    float bb1 = fc1b[n0 + lr];
    #pragma unroll
    for (int mt = 0; mt < 2; ++mt){
      i32x4 aA = {0,0,0,0}, aB = {0,0,0,0};
      const char* p0 = L + base1  + 8192 + mB0*128 + mt*2048;
      const char* p1 = L + base1x + 8192 + mB0*128 + mt*2048;
      #pragma unroll
      for (int ks = 0; ks < 2; ++ks){
        const char* pp = ks ? p1 : p0;
        i32x4 Ah = *(const i32x4*)pp;
        i32x4 Al = *(const i32x4*)(pp + LOD);
        i32x4 Bh = *(const i32x4*)(ws + QF1OFF + ((long)((grp*2+ks)*2+0)*64 + lane)*16);
        i32x4 Bl = *(const i32x4*)(ws + QF1OFF + ((long)((grp*2+ks)*2+1)*64 + lane)*16);
        aA = MFMA64(Ah, Bh, aA); aB = MFMA64(Ah, Bl, aB); aB = MFMA64(Al, Bh, aB);
      }
      #pragma unroll
      for (int e = 0; e < 4; ++e)
        *(float*)(L + cbase + ((4 + mt)*4 + e)*2048) =
            (16384.f*(float)aA[e] + 128.f*(float)aB[e])*sf1 + bb1;
    }
  }
  __syncthreads();

  // ---- tile lambdas (pofs = read-buf offset, qofs = write-buf offset)
  auto l1_one = [&](int mt, int pofs, int qofs){
    f32x4 kA = *(const f32x4*)(L + kad1);
    f32x4 kC = *(const f32x4*)(L + kad1 + 2048);
    float tg0[4], tg1[4], tg2[4], tg3[4];
    #pragma unroll
    for (int gp = 0; gp < 2; ++gp){
      i32x4 aA0 = {0,0,0,0}, aB0 = {0,0,0,0};
      i32x4 aA1 = {0,0,0,0}, aB1 = {0,0,0,0};
      {
        const char* pp = L + base0 + pofs + mt*2048;     // ks0: h0
        i32x4 Hh = *(const i32x4*)pp, Hl = *(const i32x4*)(pp + LOD);
        aA0 = MFMA64(Hh, WB1[2*gp  ][0][0], aA0);
        aB0 = MFMA64(Hh, WB1[2*gp  ][0][1], aB0);
        aB0 = MFMA64(Hl, WB1[2*gp  ][0][0], aB0);
        aA1 = MFMA64(Hh, WB1[2*gp+1][0][0], aA1);
        aB1 = MFMA64(Hh, WB1[2*gp+1][0][1], aB1);
        aB1 = MFMA64(Hl, WB1[2*gp+1][0][0], aB1);
      }
      {
        const char* pp = L + base1 + pofs + mt*2048;     // ks1: h1 [0,64)
        i32x4 Hh = *(const i32x4*)pp, Hl = *(const i32x4*)(pp + LOD);
        aA0 = MFMA64(Hh, WB1[2*gp  ][1][0], aA0);
        aB0 = MFMA64(Hh, WB1[2*gp  ][1][1], aB0);
        aB0 = MFMA64(Hl, WB1[2*gp  ][1][0], aB0);
        aA1 = MFMA64(Hh, WB1[2*gp+1][1][0], aA1);
        aB1 = MFMA64(Hh, WB1[2*gp+1][1][1], aB1);
        aB1 = MFMA64(Hl, WB1[2*gp+1][1][0], aB1);
      }
      {
        const char* pp = L + base1x + pofs + mt*2048;    // ks2: h1 [64,128)
        i32x4 Hh = *(const i32x4*)pp, Hl = *(const i32x4*)(pp + LOD);
        aA0 = MFMA64(Hh, WB1[2*gp  ][2][0], aA0);
        aB0 = MFMA64(Hh, WB1[2*gp  ][2][1], aB0);
        aB0 = MFMA64(Hl, WB1[2*gp  ][2][0], aB0);
        aA1 = MFMA64(Hh, WB1[2*gp+1][2][0], aA1);
        aB1 = MFMA64(Hh, WB1[2*gp+1][2][1], aB1);
        aB1 = MFMA64(Hl, WB1[2*gp+1][2][0], aB1);
      }
      #pragma unroll
      for (int e = 0; e < 4; ++e){
        float tA = fmaf(fmaf((float)aB0[e], 0.0078125f, (float)aA0[e]), kA[2*gp  ], kC[2*gp  ]);
        float tB = fmaf(fmaf((float)aB1[e], 0.0078125f, (float)aA1[e]), kA[2*gp+1], kC[2*gp+1]);
        if (gp == 0){ tg0[e] = tA; tg1[e] = tB; }
        else        { tg2[e] = tA; tg3[e] = tB; }
      }
    }
    int hb[4], lb[4];
    #pragma unroll
    for (int e = 0; e < 4; ++e){
      float cc = *(const float*)(L + cbase + (mt*4 + e)*2048);
      cellupd(tg0[e], tg1[e], tg2[e], tg3[e], cc, hb[e], lb[e]);
      *(float*)(L + cbase + (mt*4 + e)*2048) = cc;
    }
    unsigned hw = pk4(hb[0], hb[1], hb[2], hb[3]);
    unsigned lw = pk4(lb[0], lb[1], lb[2], lb[3]);
    const int sb = cst1 + qofs + mt*2048;
    #pragma unroll
    for (int e = 0; e < 4; ++e){
      char* pa = L + (sb ^ (e << 4));
      pa[e*128]       = (char)(hw >> (8*e));
      pa[e*128 + LOD] = (char)(lw >> (8*e));
    }
  };

  auto l0_one = [&](int mt, int pofs, int xofs, int qofs){
    f32x4 kA = *(const f32x4*)(L + kad1 + 4096);
    f32x4 kC = *(const f32x4*)(L + kad1 + 6144);
    const char* px = L + xrdb + xofs + mt*512;
    long Xh = *(const long*)px, Xl = *(const long*)(px + LOD);
    const char* ph = L + base0w + pofs + mt*2048;
    i32x4 Hh = *(const i32x4*)ph, Hl = *(const i32x4*)(ph + LOD);
    float tg[4][4];
    #pragma unroll
    for (int g = 0; g < 4; ++g){
      const i32x4 z = {0,0,0,0};
      long Wx0 = *(const long*)(L + owxb + g*1024);
      long Wx1 = *(const long*)(L + owxb + g*1024 + 512);
      i32x4 hA = MFMA64(Hh, WB0h[g][0], z);
      i32x4 hB = MFMA64(Hh, WB0h[g][1], z);
      hB = MFMA64(Hl, WB0h[g][0], hB);
      i32x4 xA = MFMA32(Xh, Wx0, z);
      i32x4 xB = MFMA32(Xh, Wx1, z);
      xB = MFMA32(Xl, Wx0, xB);
      #pragma unroll
      for (int e = 0; e < 4; ++e){
        float fA = (float)(hA[e] + (xA[e] << 3));
        float fB = (float)(hB[e] + (xB[e] << 3));
        tg[g][e] = fmaf(fmaf(fB, 0.0078125f, fA), kA[g], kC[g]);
      }
    }
    int hb[4], lb[4];
    #pragma unroll
    for (int e = 0; e < 4; ++e){
      float cc = *(const float*)(L + cbase + ((4 + mt)*4 + e)*2048);
      cellupd(tg[0][e], tg[1][e], tg[2][e], tg[3][e], cc, hb[e], lb[e]);
      *(float*)(L + cbase + ((4 + mt)*4 + e)*2048) = cc;
    }
    unsigned hw = pk4(hb[0], hb[1], hb[2], hb[3]);
    unsigned lw = pk4(lb[0], lb[1], lb[2], lb[3]);
    const int sb = cst0 + qofs + mt*2048;
    #pragma unroll
    for (int e = 0; e < 4; ++e){
      char* pa = L + (sb ^ (e << 4));
      pa[e*128]       = (char)(hw >> (8*e));
      pa[e*128 + LOD] = (char)(lw >> (8*e));
    }
  };

  // ---- pre-loop: L0(0) (reads h0(-1)=zeros buf1, x(0) buf0) -> h0(0) buf0; stage x(1)->buf1
  {
    float4 xv; const bool doX = tid < 192;
    if (doX) xv = *(const float4*)&x[((size_t)(rowBase + xr)*T + 1)*F + xq*4];
    l0_one(0, 8192, 0, 0);
    l0_one(1, 8192, 0, 0);
    if (doX){
      unsigned lw, hw = quantw(xv, lw);
      char* pw = L + xst + 2048;
      *(unsigned*)pw = hw; *(unsigned*)(pw + LOD) = lw;
    }
    __syncthreads();
  }

  // ---- main loop: M(i) computes L1(i) + L0(i+1); 1 barrier per step
  for (int j = 0; j < 7; ++j){
    { // M(2j): reads buf0 (h0,h1), x buf1; writes buf1; stage x(2j+2)->buf0
      float4 xv; const bool doX = tid < 192;
      if (doX) xv = *(const float4*)&x[((size_t)(rowBase + xr)*T + (2*j + 2))*F + xq*4];
      l1_one(0, 0, 8192);
      l1_one(1, 0, 8192);
      l0_one(0, 0, 2048, 8192);
      l1_one(2, 0, 8192);
      l0_one(1, 0, 2048, 8192);
      l1_one(3, 0, 8192);
      if (doX){
        unsigned lw, hw = quantw(xv, lw);
        char* pw = L + xst;
        *(unsigned*)pw = hw; *(unsigned*)(pw + LOD) = lw;
      }
      __syncthreads();
    }
    { // M(2j+1): reads buf1, x buf0; writes buf0; stage x(2j+3)->buf1 (j<6)
      float4 xv; const bool doX = (j < 6) && (tid < 192);
      if (doX) xv = *(const float4*)&x[((size_t)(rowBase + xr)*T + (2*j + 3))*F + xq*4];
      l1_one(0, 8192, 0);
      l1_one(1, 8192, 0);
      l0_one(0, 8192, 0, 0);
      l1_one(2, 8192, 0);
      l0_one(1, 8192, 0, 0);
      l1_one(3, 8192, 0);
      if (doX){
        unsigned lw, hw = quantw(xv, lw);
        char* pw = L + xst + 2048;
        *(unsigned*)pw = hw; *(unsigned*)(pw + LOD) = lw;
      }
      __syncthreads();
    }
  }

  // ---- final: L1(14) (reads buf0) -> h1(15) into buf1
  {
    l1_one(0, 0, 8192);
    l1_one(1, 0, 8192);
    l1_one(2, 0, 8192);
    l1_one(3, 0, 8192);
    __syncthreads();
  }

  // ---- epilogue: pred = h1 . w_eff + b_eff (h1 in buf1)
  {
    int r = tid >> 3, s = tid & 7;
    const float* wE = (const float*)(L + OWE);
    float sum = 0.f;
    #pragma unroll
    for (int cc = 0; cc < 16; ++cc){
      int c = s*16 + cc;
      const char* pe = L + OH1 + 8192 + r*128 + (c ^ ((r & 7) << 4));
      float hq = 128.f*(float)(signed char)pe[0] + (float)(signed char)pe[LOD];
      sum += hq * HINV * wE[c];
    }
    sum += __shfl_down(sum, 4);
    sum += __shfl_down(sum, 2);
    sum += __shfl_down(sum, 1);
    if (s == 0) out[rowBase + r] = sum + wE[128];
  }
}

extern "C" void kernel_launch(void* const* d_in, const int* in_sizes, int n_in,
                              void* d_out, int out_size, void* d_ws, size_t ws_size,
                              hipStream_t stream) {
  const float* x    = (const float*)d_in[0];
  const float* cs   = (const float*)d_in[1];
  const float* fc1w = (const float*)d_in[2];
  const float* fc1b = (const float*)d_in[3];
  const float* fc2w = (const float*)d_in[4];
  const float* fc2b = (const float*)d_in[5];
  const float* w0i  = (const float*)d_in[6];
  const float* w0h  = (const float*)d_in[7];
  const float* b0i  = (const float*)d_in[8];
  const float* b0h  = (const float*)d_in[9];
  const float* w1i  = (const float*)d_in[10];
  const float* w1h  = (const float*)d_in[11];
  const float* b1i  = (const float*)d_in[12];
  const float* b1h  = (const float*)d_in[13];
  const float* d1w  = (const float*)d_in[14];
  const float* d1b  = (const float*)d_in[15];
  const float* d2w  = (const float*)d_in[16];
  const float* d2b  = (const float*)d_in[17];

  char* ws = (char*)d_ws;
  prequant<<<960, 64, 0, stream>>>(fc1w, fc2w, w0i, w0h, w1i, w1h, ws);

  const int Btot = in_sizes[0] / (T * F);   // 131072
  const int grid = Btot / R;                // 2048
  caurec<<<grid, 512, 0, stream>>>(x, cs, fc1b, fc2b, b0i, b0h, b1i, b1h,
                                   d1w, d1b, d2w, d2b, ws, (float*)d_out);
}

// Round 8
// 904.015 us; speedup vs baseline: 2.6485x; 1.0371x over previous
//
#include <hip/hip_runtime.h>

// CauRecNet: 2-layer LSTM, B=131072 x T=15, i8-pair (14-bit fixed point) MFMA.
// Round 8: round-7 + VALU diet: single-rcp fused (i,f,g) cell update (4exp+2rcp),
// integer gate-combine ((aA<<7)+aB, kA pre-divided by 128), magic-quant split
// without -MAGI (bias vanishes in byte-select). ~-20% VALU issue.

typedef int   i32x4 __attribute__((ext_vector_type(4)));
typedef float f32x4 __attribute__((ext_vector_type(4)));

#define DEV static __device__ __forceinline__

DEV float fexp2(float x){ return __builtin_amdgcn_exp2f(x); }
DEV float frcp (float x){ return __builtin_amdgcn_rcpf(x); }

#if __has_builtin(__builtin_amdgcn_sbfe)
DEV int sbfe7(int x){ return __builtin_amdgcn_sbfe(x, 0, 7); }
#else
DEV int sbfe7(int x){ return (x << 25) >> 25; }
#endif

#define MFMA64(A,B,C) __builtin_amdgcn_mfma_i32_16x16x64_i8(A,B,C,0,0,0)
#define MFMA32(A,B,C) __builtin_amdgcn_mfma_i32_16x16x32_i8(A,B,C,0,0,0)

constexpr int T = 15, F = 12, CS = 96;
constexpr int R = 64;

// d_ws layout (bytes) — unchanged
constexpr int Q1OFF  = 0;
constexpr int Q0OFF  = 196608;
constexpr int QF2OFF = 245760;
constexpr int QF1OFF = 278528;
constexpr int S1OFF  = 294912;
constexpr int S0OFF  = 296960;
constexpr int SF2OFF = 297984;
constexpr int SF1OFF = 298496;

constexpr float QM   = 16128.0f;
constexpr float QMX  = 2016.0f;
constexpr float HINV = 1.0f/16128.0f;
constexpr float NL2E = -1.44269504f, PL2E2 = 2.88539008f;
constexpr float MAGIC = 12582912.0f;   // 1.5 * 2^23 (low 7 bits of bit pattern are 0)

// LDS map (hi regions; lo mirror at +LOD for h0/h1/x)
constexpr int OH0 = 0;       // h0 hi: buf0 @0, buf1 @8192   (64 rows x 128B)
constexpr int OH1 = 16384;   // h1 hi: buf0 @16384, buf1 @24576
constexpr int OX  = 32768;   // x  hi: buf0 @32768, buf1 @34816 (64 x 32B)
constexpr int OKC = 36864;   // kconst: L1kA@+0, L1kC@+2048, L0kA@+4096, L0kC@+6144
constexpr int LOD = 45056;   // lo mirror delta
constexpr int OWE = 81920;   // wEff floats (129)
constexpr int OWX = 82944;   // W0 x-fragments [16 chunks][1024B] = 16384
constexpr int OC  = 99328;   // c-states: [24 slots][512 thr][f32] = 49152
constexpr int LDSB= 148480;

// ---------------- weight pre-quantization (unchanged) ----------------
__global__ __launch_bounds__(64) void prequant(
    const float* __restrict__ fc1w, const float* __restrict__ fc2w,
    const float* __restrict__ w0i,  const float* __restrict__ w0h,
    const float* __restrict__ w1i,  const float* __restrict__ w1h,
    char* __restrict__ ws)
{
  const int r = blockIdx.x, j = threadIdx.x;
  float v[3] = {0.f, 0.f, 0.f};
  int   kk[3] = {-1, -1, -1};
  int type, n;
  if (r < 512){ type = 0; n = r; }
  else if (r < 768){ type = 1; n = r - 512; }
  else if (r < 896){ type = 2; n = r - 768; }
  else { type = 3; n = r - 896; }

  if (type == 0){
    for (int c = 0; c < 3; ++c){
      int k = j + c*64; kk[c] = k;
      v[c] = (k < 64) ? w1i[n*64 + k] : w1h[n*128 + (k - 64)];
    }
  } else if (type == 1){
    kk[0] = j;
    v[0] = (j < 32) ? ((j < 12) ? w0i[n*12 + j] : 0.f) : w0h[n*64 + (j - 32)];
    if (j < 32){ kk[1] = 64 + j; v[1] = w0h[n*64 + (32 + j)]; }
  } else {
    const float* fw = (type == 2) ? fc2w : fc1w;
    for (int c = 0; c < 2; ++c){
      int k = j + c*64; kk[c] = k;
      v[c] = (k < 96) ? fw[n*CS + k] : 0.f;
    }
  }
  float m = fmaxf(fmaxf(fabsf(v[0]), fabsf(v[1])), fabsf(v[2]));
  #pragma unroll
  for (int d = 32; d; d >>= 1) m = fmaxf(m, __shfl_xor(m, d));
  float s   = (m > 0.f) ? (m / 16120.0f) : 1.0f;
  float inv = (m > 0.f) ? (16120.0f / m) : 0.0f;
  if (j == 0){
    float* sp = (float*)(ws + (type==0 ? S1OFF : type==1 ? S0OFF : type==2 ? SF2OFF : SF1OFF));
    sp[n] = s;
  }
  const int lr = n & 15;
  #pragma unroll
  for (int c = 0; c < 3; ++c){
    int k = kk[c];
    if (k < 0) continue;
    float q  = rintf(v[c] * inv);
    float hf = rintf(q * 0.0078125f);
    int hi = (int)hf, lo = (int)(q - hf*128.0f);
    long offh, offl;
    if (type == 0){
      int g = n >> 7, wv = (n & 127) >> 4;
      int ks = k >> 6, lg = (k >> 4) & 3, jj = k & 15, lane = lg*16 + lr;
      long base = Q1OFF + (((long)((wv*4+g)*3+ks)*2*64) + lane)*16 + jj;
      offh = base; offl = base + 1024;
    } else if (type == 1){
      int g = n >> 6, grp = (n & 63) >> 4;
      long b0 = Q0OFF + (long)(grp*4+g)*3072;
      if (k < 32){ int lg = (k>>3)&3, jj = k&7, lane = lg*16+lr;
        offh = b0 + lane*8 + jj; offl = offh + 512;
      } else { int kh = k-32, lg = kh>>4, jj = kh&15, lane = lg*16+lr;
        offh = b0 + 1024 + lane*16 + jj; offl = offh + 1024;
      }
    } else {
      int ks = k >> 6, lg = (k>>4)&3, jj = k&15, lane = lg*16+lr;
      int grp = n >> 4;
      long base = (type==2 ? QF2OFF : QF1OFF) + ((long)((grp*2+ks)*2)*64 + lane)*16 + jj;
      offh = base; offl = base + 1024;
    }
    ws[offh] = (char)hi; ws[offl] = (char)lo;
  }
}

// ---------------- helpers ----------------
DEV unsigned pk4(int b0, int b1, int b2, int b3){
  unsigned p01 = __builtin_amdgcn_perm((unsigned)b1, (unsigned)b0, 0x00000400u);
  unsigned p23 = __builtin_amdgcn_perm((unsigned)b3, (unsigned)b2, 0x04000000u);
  return __builtin_amdgcn_perm(p23, p01, 0x07060100u);
}

// 4-exp 2-rcp cellupd. tmp = sigma(f)*c + sigma(i)*tanh(g) computed over a
// common denominator (one rcp); products bounded (<1e21) — no overflow.
// Quant split keeps the MAGIC bias: low 7 bits of MAGIC's pattern are 0 and
// pk4 keeps only the low byte, so hi-byte/lo are exact without -MAGI.
DEV void cellupd(float t0, float t1, float t2, float t3,
                 float& c, int& hi, int& lo){
  float ei = fexp2(t0);                 // e^{-a_i}
  float ef = fexp2(t1);                 // e^{-a_f}
  float eg = fexp2(t2);                 // e^{2 a_g}
  float eo = fexp2(t3);                 // e^{-a_o}
  float e1 = 1.f + ei;
  float e2 = eg + 1.f;
  float e3 = 1.f + ef;
  float m1 = e1 * e2;
  float num = fmaf(c, m1, (eg - 1.f) * e3);
  float tmp = num * frcp(m1 * e3);      // f*c + i*g
  c += tmp;
  float tc = fminf(tmp, 12.0f);         // overflow clamp (pos side only)
  float ec = fexp2(tc * PL2E2);
  float h  = (ec - 1.f) * frcp((1.f + eo) * (ec + 1.f));  // sigmoid(o)*tanh(tmp)
  int qi = __float_as_int(fmaf(h, QM, MAGIC));
  lo = sbfe7(qi);
  hi = (qi - lo) >> 7;                  // low byte == true hi
}

DEV unsigned quantw(float4 v, unsigned& lw){
  int h[4], l[4];
  float vv[4] = {v.x, v.y, v.z, v.w};
  #pragma unroll
  for (int e = 0; e < 4; ++e){
    int qi = __float_as_int(fmaf(vv[e], QMX, MAGIC));
    l[e] = sbfe7(qi);
    h[e] = (qi - l[e]) >> 7;
  }
  lw = pk4(l[0], l[1], l[2], l[3]);
  return pk4(h[0], h[1], h[2], h[3]);
}

// ---------------- main recurrence kernel ----------------
__global__ __launch_bounds__(512, 2) void caurec(
    const float* __restrict__ x,    const float* __restrict__ cs,
    const float* __restrict__ fc1b, const float* __restrict__ fc2b,
    const float* __restrict__ b0i,  const float* __restrict__ b0h,
    const float* __restrict__ b1i,  const float* __restrict__ b1h,
    const float* __restrict__ d1w,  const float* __restrict__ d1b,
    const float* __restrict__ d2w,  const float* __restrict__ d2b,
    const char* __restrict__ ws,    float* __restrict__ out)
{
  __shared__ alignas(16) char L[LDSB];

  const int tid  = threadIdx.x;
  const int wave = tid >> 6, lane = tid & 63, lr = lane & 15, lg = lane >> 4;
  const int n0   = (wave & 3) * 16, mB0 = (wave >> 2) * 32, n1 = wave * 16;
  const int grp  = wave & 3;
  const int rowBase = blockIdx.x * R;
  const int sw8  = (lr & 7) << 4;

  // per-lane bases
  const int base0  = OH0 + lr*128 + ((lg*16) ^ sw8);   // h0 A-read (+mt*2048, +pofs)
  const int base0w = base0 + mB0*128;                  // h0 A-read for l0 tiles
  const int base1  = OH1 + lr*128 + ((lg*16) ^ sw8);   // h1 ks1
  const int base1x = base1 ^ 64;                       // h1 ks2
  const int xrdb   = OX + (mB0 + lr)*32 + lg*8;
  const int kad1   = OKC + wave*256 + lr*16;
  const int cst1   = OH1 + (lg*4)*128 + ((n1 + lr) ^ ((lg & 1) << 6));
  const int cst0   = OH0 + (mB0 + lg*4)*128 + ((n0 + lr) ^ ((lg & 1) << 6));
  const int owxb   = OWX + grp*4096 + lane*8;
  const int cbase  = OC + tid*4;
  const int xr = tid/3, xq = tid - (tid/3)*3;
  const int xst = OX + xr*32 + xq*4;

  // ---- zero: h0 b1 + h1 b0 (hi), x (hi), and lo mirrors
  {
    unsigned* W = (unsigned*)L;
    for (int i = tid; i < 4096; i += 512) W[2048  + i] = 0u;  // [8192,24576)
    for (int i = tid; i < 1024; i += 512) W[8192  + i] = 0u;  // [32768,36864)
    for (int i = tid; i < 4096; i += 512) W[13312 + i] = 0u;  // [53248,69632)
    for (int i = tid; i < 1024; i += 512) W[19456 + i] = 0u;  // [77824,81920)
  }
  __syncthreads();

  // ---- stage: cs -> h1 buf1; x(0) -> x buf0; wEff; kconst; W0x -> LDS
  {
    int r = tid >> 3, cg = (tid & 7) * 16;
    float vv[16];
    #pragma unroll
    for (int u = 0; u < 4; ++u){
      if (cg + u*4 < CS){
        float4 v = *(const float4*)&cs[(size_t)(rowBase + r)*CS + cg + u*4];
        vv[u*4] = v.x; vv[u*4+1] = v.y; vv[u*4+2] = v.z; vv[u*4+3] = v.w;
      } else { vv[u*4] = vv[u*4+1] = vv[u*4+2] = vv[u*4+3] = 0.f; }
    }
    i32x4 HV, LV;
    #pragma unroll
    for (int u = 0; u < 4; ++u){
      unsigned lw, hw = quantw(make_float4(vv[u*4], vv[u*4+1], vv[u*4+2], vv[u*4+3]), lw);
      HV[u] = (int)hw; LV[u] = (int)lw;
    }
    char* pcs = L + OH1 + 8192 + r*128 + (cg ^ ((r & 7) << 4));
    *(i32x4*)pcs = HV;
    *(i32x4*)(pcs + LOD) = LV;
  }
  if (tid < 192){
    float4 v = *(const float4*)&x[((size_t)(rowBase + xr)*T + 0)*F + xq*4];
    unsigned lw, hw = quantw(v, lw);
    char* pw = L + xst;                       // x(0) -> buf0
    *(unsigned*)pw = hw; *(unsigned*)(pw + LOD) = lw;
  }
  if (tid < 128){
    float s = 0.f;
    for (int a = 0; a < 64; ++a) s += d2w[a] * d1w[a*128 + tid];
    ((float*)(L + OWE))[tid] = s;
  } else if (tid == 128){
    float s = 0.f;
    for (int a = 0; a < 64; ++a) s += d2w[a] * d1b[a];
    ((float*)(L + OWE))[128] = s + d2b[0];
  }
  if (lg == 0){
    const float* S1p = (const float*)(ws + S1OFF);
    const float* S0p = (const float*)(ws + S0OFF);
    f32x4 a1, c1k, a0, c0k;
    #pragma unroll
    for (int g = 0; g < 4; ++g){
      float f = (g == 2) ? PL2E2 : NL2E;
      // kA pre-divided by 128: consumed as t = fma((float)((aA<<7)+aB), kA, kC)
      a1[g]  = f * 128.f * (S1p[g*128 + n1 + lr] * HINV);
      c1k[g] = f * (b1i[g*128 + n1 + lr] + b1h[g*128 + n1 + lr]);
      a0[g]  = f * 128.f * (S0p[g*64 + n0 + lr] * HINV);
      c0k[g] = f * (b0i[g*64 + n0 + lr] + b0h[g*64 + n0 + lr]);
    }
    char* pk = L + kad1;
    *(f32x4*)pk          = a1;
    *(f32x4*)(pk + 2048) = c1k;
    *(f32x4*)(pk + 4096) = a0;
    *(f32x4*)(pk + 6144) = c0k;
  }
  // W0 x-fragments -> LDS (16 chunks x 1024B, mirror of ws layout)
  #pragma unroll
  for (int k = 0; k < 4; ++k){
    int i = tid + k*512;
    int c16 = i >> 7, rem = i & 127;
    *(long*)(L + OWX + c16*1024 + rem*8) =
        *(const long*)(ws + Q0OFF + (long)c16*3072 + rem*8);
  }

  // persistent weight fragments (global loads; no LDS dep)
  i32x4 WB1[4][3][2];
  #pragma unroll
  for (int g = 0; g < 4; ++g)
    #pragma unroll
    for (int ks = 0; ks < 3; ++ks)
      #pragma unroll
      for (int sp = 0; sp < 2; ++sp)
        WB1[g][ks][sp] = *(const i32x4*)(ws + Q1OFF + ((long)(((wave*4+g)*3+ks)*2+sp)*64 + lane)*16);
  i32x4 WB0h[4][2];
  #pragma unroll
  for (int g = 0; g < 4; ++g){
    const char* b0p = ws + Q0OFF + (long)(grp*4+g)*3072;
    #pragma unroll
    for (int sp = 0; sp < 2; ++sp)
      WB0h[g][sp] = *(const i32x4*)(b0p + 1024 + sp*1024 + lane*16);
  }
  __syncthreads();

  // ---- init GEMMs from cs staged in h1 buf1 -> c states into LDS
  {
    float sf2 = ((const float*)(ws + SF2OFF))[n1 + lr] * (HINV * 8.0f);
    float bb2 = fc2b[n1 + lr];
    #pragma unroll
    for (int mt = 0; mt < 4; ++mt){
      i32x4 aA = {0,0,0,0}, aB = {0,0,0,0};
      const char* p0 = L + base1  + 8192 + mt*2048;
      const char* p1 = L + base1x + 8192 + mt*2048;
      #pragma unroll
      for (int ks = 0; ks < 2; ++ks){
        const char* pp = ks ? p1 : p0;
        i32x4 Ah = *(const i32x4*)pp;
        i32x4 Al = *(const i32x4*)(pp + LOD);
        i32x4 Bh = *(const i32x4*)(ws + QF2OFF + ((long)((wave*2+ks)*2+0)*64 + lane)*16);
        i32x4 Bl = *(const i32x4*)(ws + QF2OFF + ((long)((wave*2+ks)*2+1)*64 + lane)*16);
        aA = MFMA64(Ah, Bh, aA); aB = MFMA64(Ah, Bl, aB); aB = MFMA64(Al, Bh, aB);
      }
      #pragma unroll
      for (int e = 0; e < 4; ++e)
        *(float*)(L + cbase + (mt*4 + e)*2048) =
            (16384.f*(float)aA[e] + 128.f*(float)aB[e])*sf2 + bb2;
    }
    float sf1 = ((const float*)(ws + SF1OFF))[n0 + lr] * (HINV * 8.0f);
    float bb1 = fc1b[n0 + lr];
    #pragma unroll
    for (int mt = 0; mt < 2; ++mt){
      i32x4 aA = {0,0,0,0}, aB = {0,0,0,0};
      const char* p0 = L + base1  + 8192 + mB0*128 + mt*2048;
      const char* p1 = L + base1x + 8192 + mB0*128 + mt*2048;
      #pragma unroll
      for (int ks = 0; ks < 2; ++ks){
        const char* pp = ks ? p1 : p0;
        i32x4 Ah = *(const i32x4*)pp;
        i32x4 Al = *(const i32x4*)(pp + LOD);
        i32x4 Bh = *(const i32x4*)(ws + QF1OFF + ((long)((grp*2+ks)*2+0)*64 + lane)*16);
        i32x4 Bl = *(const i32x4*)(ws + QF1OFF + ((long)((grp*2+ks)*2+1)*64 + lane)*16);
        aA = MFMA64(Ah, Bh, aA); aB = MFMA64(Ah, Bl, aB); aB = MFMA64(Al, Bh, aB);
      }
      #pragma unroll
      for (int e = 0; e < 4; ++e)
        *(float*)(L + cbase + ((4 + mt)*4 + e)*2048) =
            (16384.f*(float)aA[e] + 128.f*(float)aB[e])*sf1 + bb1;
    }
  }
  __syncthreads();

  // ---- tile lambdas (pofs = read-buf offset, qofs = write-buf offset)
  auto l1_one = [&](int mt, int pofs, int qofs){
    f32x4 kA = *(const f32x4*)(L + kad1);
    f32x4 kC = *(const f32x4*)(L + kad1 + 2048);
    float tg0[4], tg1[4], tg2[4], tg3[4];
    #pragma unroll
    for (int gp = 0; gp < 2; ++gp){
      i32x4 aA0 = {0,0,0,0}, aB0 = {0,0,0,0};
      i32x4 aA1 = {0,0,0,0}, aB1 = {0,0,0,0};
      {
        const char* pp = L + base0 + pofs + mt*2048;     // ks0: h0
        i32x4 Hh = *(const i32x4*)pp, Hl = *(const i32x4*)(pp + LOD);
        aA0 = MFMA64(Hh, WB1[2*gp  ][0][0], aA0);
        aB0 = MFMA64(Hh, WB1[2*gp  ][0][1], aB0);
        aB0 = MFMA64(Hl, WB1[2*gp  ][0][0], aB0);
        aA1 = MFMA64(Hh, WB1[2*gp+1][0][0], aA1);
        aB1 = MFMA64(Hh, WB1[2*gp+1][0][1], aB1);
        aB1 = MFMA64(Hl, WB1[2*gp+1][0][0], aB1);
      }
      {
        const char* pp = L + base1 + pofs + mt*2048;     // ks1: h1 [0,64)
        i32x4 Hh = *(const i32x4*)pp, Hl = *(const i32x4*)(pp + LOD);
        aA0 = MFMA64(Hh, WB1[2*gp  ][1][0], aA0);
        aB0 = MFMA64(Hh, WB1[2*gp  ][1][1], aB0);
        aB0 = MFMA64(Hl, WB1[2*gp  ][1][0], aB0);
        aA1 = MFMA64(Hh, WB1[2*gp+1][1][0], aA1);
        aB1 = MFMA64(Hh, WB1[2*gp+1][1][1], aB1);
        aB1 = MFMA64(Hl, WB1[2*gp+1][1][0], aB1);
      }
      {
        const char* pp = L + base1x + pofs + mt*2048;    // ks2: h1 [64,128)
        i32x4 Hh = *(const i32x4*)pp, Hl = *(const i32x4*)(pp + LOD);
        aA0 = MFMA64(Hh, WB1[2*gp  ][2][0], aA0);
        aB0 = MFMA64(Hh, WB1[2*gp  ][2][1], aB0);
        aB0 = MFMA64(Hl, WB1[2*gp  ][2][0], aB0);
        aA1 = MFMA64(Hh, WB1[2*gp+1][2][0], aA1);
        aB1 = MFMA64(Hh, WB1[2*gp+1][2][1], aB1);
        aB1 = MFMA64(Hl, WB1[2*gp+1][2][0], aB1);
      }
      #pragma unroll
      for (int e = 0; e < 4; ++e){
        int qA = (aA0[e] << 7) + aB0[e];                 // v_lshl_add
        int qB = (aA1[e] << 7) + aB1[e];
        float tA = fmaf((float)qA, kA[2*gp  ], kC[2*gp  ]);
        float tB = fmaf((float)qB, kA[2*gp+1], kC[2*gp+1]);
        if (gp == 0){ tg0[e] = tA; tg1[e] = tB; }
        else        { tg2[e] = tA; tg3[e] = tB; }
      }
    }
    int hb[4], lb[4];
    #pragma unroll
    for (int e = 0; e < 4; ++e){
      float cc = *(const float*)(L + cbase + (mt*4 + e)*2048);
      cellupd(tg0[e], tg1[e], tg2[e], tg3[e], cc, hb[e], lb[e]);
      *(float*)(L + cbase + (mt*4 + e)*2048) = cc;
    }
    unsigned hw = pk4(hb[0], hb[1], hb[2], hb[3]);
    unsigned lw = pk4(lb[0], lb[1], lb[2], lb[3]);
    const int sb = cst1 + qofs + mt*2048;
    #pragma unroll
    for (int e = 0; e < 4; ++e){
      char* pa = L + (sb ^ (e << 4));
      pa[e*128]       = (char)(hw >> (8*e));
      pa[e*128 + LOD] = (char)(lw >> (8*e));
    }
  };

  auto l0_one = [&](int mt, int pofs, int xofs, int qofs){
    f32x4 kA = *(const f32x4*)(L + kad1 + 4096);
    f32x4 kC = *(const f32x4*)(L + kad1 + 6144);
    const char* px = L + xrdb + xofs + mt*512;
    long Xh = *(const long*)px, Xl = *(const long*)(px + LOD);
    const char* ph = L + base0w + pofs + mt*2048;
    i32x4 Hh = *(const i32x4*)ph, Hl = *(const i32x4*)(ph + LOD);
    float tg[4][4];
    #pragma unroll
    for (int g = 0; g < 4; ++g){
      const i32x4 z = {0,0,0,0};
      long Wx0 = *(const long*)(L + owxb + g*1024);
      long Wx1 = *(const long*)(L + owxb + g*1024 + 512);
      i32x4 hA = MFMA64(Hh, WB0h[g][0], z);
      i32x4 hB = MFMA64(Hh, WB0h[g][1], z);
      hB = MFMA64(Hl, WB0h[g][0], hB);
      i32x4 xA = MFMA32(Xh, Wx0, z);
      i32x4 xB = MFMA32(Xh, Wx1, z);
      xB = MFMA32(Xl, Wx0, xB);
      #pragma unroll
      for (int e = 0; e < 4; ++e){
        int u = hA[e] + (xA[e] << 3);                    // v_lshl_add
        int v = hB[e] + (xB[e] << 3);
        int q = (u << 7) + v;                            // v_lshl_add
        tg[g][e] = fmaf((float)q, kA[g], kC[g]);
      }
    }
    int hb[4], lb[4];
    #pragma unroll
    for (int e = 0; e < 4; ++e){
      float cc = *(const float*)(L + cbase + ((4 + mt)*4 + e)*2048);
      cellupd(tg[0][e], tg[1][e], tg[2][e], tg[3][e], cc, hb[e], lb[e]);
      *(float*)(L + cbase + ((4 + mt)*4 + e)*2048) = cc;
    }
    unsigned hw = pk4(hb[0], hb[1], hb[2], hb[3]);
    unsigned lw = pk4(lb[0], lb[1], lb[2], lb[3]);
    const int sb = cst0 + qofs + mt*2048;
    #pragma unroll
    for (int e = 0; e < 4; ++e){
      char* pa = L + (sb ^ (e << 4));
      pa[e*128]       = (char)(hw >> (8*e));
      pa[e*128 + LOD] = (char)(lw >> (8*e));
    }
  };

  // ---- pre-loop: L0(0) (reads h0(-1)=zeros buf1, x(0) buf0) -> h0(0) buf0; stage x(1)->buf1
  {
    float4 xv; const bool doX = tid < 192;
    if (doX) xv = *(const float4*)&x[((size_t)(rowBase + xr)*T + 1)*F + xq*4];
    l0_one(0, 8192, 0, 0);
    l0_one(1, 8192, 0, 0);
    if (doX){
      unsigned lw, hw = quantw(xv, lw);
      char* pw = L + xst + 2048;
      *(unsigned*)pw = hw; *(unsigned*)(pw + LOD) = lw;
    }
    __syncthreads();
  }

  // ---- main loop: M(i) computes L1(i) + L0(i+1); 1 barrier per step
  for (int j = 0; j < 7; ++j){
    { // M(2j): reads buf0 (h0,h1), x buf1; writes buf1; stage x(2j+2)->buf0
      float4 xv; const bool doX = tid < 192;
      if (doX) xv = *(const float4*)&x[((size_t)(rowBase + xr)*T + (2*j + 2))*F + xq*4];
      l1_one(0, 0, 8192);
      l1_one(1, 0, 8192);
      l0_one(0, 0, 2048, 8192);
      l1_one(2, 0, 8192);
      l0_one(1, 0, 2048, 8192);
      l1_one(3, 0, 8192);
      if (doX){
        unsigned lw, hw = quantw(xv, lw);
        char* pw = L + xst;
        *(unsigned*)pw = hw; *(unsigned*)(pw + LOD) = lw;
      }
      __syncthreads();
    }
    { // M(2j+1): reads buf1, x buf0; writes buf0; stage x(2j+3)->buf1 (j<6)
      float4 xv; const bool doX = (j < 6) && (tid < 192);
      if (doX) xv = *(const float4*)&x[((size_t)(rowBase + xr)*T + (2*j + 3))*F + xq*4];
      l1_one(0, 8192, 0);
      l1_one(1, 8192, 0);
      l0_one(0, 8192, 0, 0);
      l1_one(2, 8192, 0);
      l0_one(1, 8192, 0, 0);
      l1_one(3, 8192, 0);
      if (doX){
        unsigned lw, hw = quantw(xv, lw);
        char* pw = L + xst + 2048;
        *(unsigned*)pw = hw; *(unsigned*)(pw + LOD) = lw;
      }
      __syncthreads();
    }
  }

  // ---- final: L1(14) (reads buf0) -> h1(15) into buf1
  {
    l1_one(0, 0, 8192);
    l1_one(1, 0, 8192);
    l1_one(2, 0, 8192);
    l1_one(3, 0, 8192);
    __syncthreads();
  }

  // ---- epilogue: pred = h1 . w_eff + b_eff (h1 in buf1)
  {
    int r = tid >> 3, s = tid & 7;
    const float* wE = (const float*)(L + OWE);
    float sum = 0.f;
    #pragma unroll
    for (int cc = 0; cc < 16; ++cc){
      int c = s*16 + cc;
      const char* pe = L + OH1 + 8192 + r*128 + (c ^ ((r & 7) << 4));
      float hq = 128.f*(float)(signed char)pe[0] + (float)(signed char)pe[LOD];
      sum += hq * HINV * wE[c];
    }
    sum += __shfl_down(sum, 4);
    sum += __shfl_down(sum, 2);
    sum += __shfl_down(sum, 1);
    if (s == 0) out[rowBase + r] = sum + wE[128];
  }
}

extern "C" void kernel_launch(void* const* d_in, const int* in_sizes, int n_in,
                              void* d_out, int out_size, void* d_ws, size_t ws_size,
                              hipStream_t stream) {
  const float* x    = (const float*)d_in[0];
  const float* cs   = (const float*)d_in[1];
  const float* fc1w = (const float*)d_in[2];
  const float* fc1b = (const float*)d_in[3];
  const float* fc2w = (const float*)d_in[4];
  const float* fc2b = (const float*)d_in[5];
  const float* w0i  = (const float*)d_in[6];
  const float* w0h  = (const float*)d_in[7];
  const float* b0i  = (const float*)d_in[8];
  const float* b0h  = (const float*)d_in[9];
  const float* w1i  = (const float*)d_in[10];
  const float* w1h  = (const float*)d_in[11];
  const float* b1i  = (const float*)d_in[12];
  const float* b1h  = (const float*)d_in[13];
  const float* d1w  = (const float*)d_in[14];
  const float* d1b  = (const float*)d_in[15];
  const float* d2w  = (const float*)d_in[16];
  const float* d2b  = (const float*)d_in[17];

  char* ws = (char*)d_ws;
  prequant<<<960, 64, 0, stream>>>(fc1w, fc2w, w0i, w0h, w1i, w1h, ws);

  const int Btot = in_sizes[0] / (T * F);   // 131072
  const int grid = Btot / R;                // 2048
  caurec<<<grid, 512, 0, stream>>>(x, cs, fc1b, fc2b, b0i, b0h, b1i, b1h,
                                   d1w, d1b, d2w, d2b, ws, (float*)d_out);
}

// Round 9
// 645.438 us; speedup vs baseline: 3.7095x; 1.4006x over previous
//
#include <hip/hip_runtime.h>

// CauRecNet: 2-layer LSTM, B=131072 x T=15. Round 9: single-plane FP16 MFMA
// (mfma_f32_16x16x32_f16, f32 accum) replacing i8-pair 3-pass. States h0/h1/x
// in LDS as f16; cell states f32 in LDS; W1 frags in regs, W0h/W0x frags in LDS.

typedef float    f32x4 __attribute__((ext_vector_type(4)));
typedef _Float16 f16x8 __attribute__((ext_vector_type(8)));
typedef _Float16 f16x4 __attribute__((ext_vector_type(4)));

#define DEV static __device__ __forceinline__

DEV float fexp2(float x){ return __builtin_amdgcn_exp2f(x); }
DEV float frcp (float x){ return __builtin_amdgcn_rcpf(x); }

#define MFMA16(A,B,C) __builtin_amdgcn_mfma_f32_16x16x32_f16(A,B,C,0,0,0)

constexpr int T = 15, F = 12, CS = 96;
constexpr int R = 64;

// d_ws layout (bytes) — f16 fragments
constexpr int Q1OFF  = 0;        // W1  [wv8][g4][ks6][lane64][16B] = 196608
constexpr int Q0HOFF = 196608;   // W0h [grp4][g4][ks2][64][16B]    = 32768
constexpr int Q0XOFF = 229376;   // W0x [grp4][g4][64][16B]         = 16384
constexpr int QF2OFF = 245760;   // fc2 [grp8][ks3][64][16B]        = 24576
constexpr int QF1OFF = 270336;   // fc1 [grp4][ks3][64][16B]        = 12288

constexpr float NL2E = -1.44269504f, PL2E2 = 2.88539008f;

// LDS map
constexpr int OH0 = 0;        // h0: 64 rows x 128B, bufs @0 / @8192
constexpr int OH1 = 16384;    // h1: 64 rows x 256B, bufs @+0 / @+16384
constexpr int OX  = 49152;    // x : 64 rows x 64B (K=32 padded), bufs @+0 / @+4096
constexpr int OKC = 57344;    // kC1 [wave][lr]x16B = 2048; kC0 @+2048 = 1024
constexpr int OWE = 60416;    // wEff floats (129)
constexpr int OWX = 61440;    // W0x frags 16K
constexpr int OWH = 77824;    // W0h frags 32K
constexpr int OC  = 110592;   // c-states [24 slots][512 thr] f32 = 49152
constexpr int LDSB= 159744;

// ---------------- weight pre-quantization -> f16 fragments ----------------
__global__ __launch_bounds__(64) void prequant(
    const float* __restrict__ fc1w, const float* __restrict__ fc2w,
    const float* __restrict__ w0i,  const float* __restrict__ w0h,
    const float* __restrict__ w1i,  const float* __restrict__ w1h,
    char* __restrict__ ws)
{
  const int r = blockIdx.x, j = threadIdx.x;
  auto put = [&](long off, float v){ *(_Float16*)(ws + off) = (_Float16)v; };
  if (r < 512){                       // W1 row n: k-space 192 = [h0(64)|h1(128)]
    int n = r, lr = n & 15, wv = (n & 127) >> 4, g = n >> 7;
    #pragma unroll
    for (int c = 0; c < 3; ++c){
      int k = j + c*64;
      float v = (k < 64) ? w1i[n*64 + k] : w1h[n*128 + (k - 64)];
      int ks = k >> 5, lane = (((k >> 3) & 3) << 4) + lr, jj = k & 7;
      put(Q1OFF + ((long)(((wv*4+g)*6+ks)*64 + lane))*16 + jj*2, v);
    }
  } else if (r < 768){                // W0 row n
    int n = r - 512, lr = n & 15, grp = (n & 63) >> 4, g = n >> 6;
    {
      int k = j;                      // h part, k 0..63
      int ks = k >> 5, lane = (((k >> 3) & 3) << 4) + lr, jj = k & 7;
      put(Q0HOFF + ((long)(((grp*4+g)*2+ks)*64 + lane))*16 + jj*2, w0h[n*64 + k]);
    }
    if (j < 32){                      // x part, k 0..31 (12 real)
      int k = j;
      int lane = (((k >> 3) & 3) << 4) + lr, jj = k & 7;
      float v = (k < 12) ? w0i[n*12 + k] : 0.f;
      put(Q0XOFF + ((long)((grp*4+g)*64 + lane))*16 + jj*2, v);
    }
  } else {                            // fc rows, k-space 96
    bool t2 = (r < 896);
    int n = t2 ? (r - 768) : (r - 896);
    const float* fw = t2 ? fc2w : fc1w;
    long base = t2 ? QF2OFF : QF1OFF;
    int lr = n & 15, grp = n >> 4;
    #pragma unroll
    for (int c = 0; c < 2; ++c){
      int k = j + c*64;
      if (k < 96){
        int ks = k >> 5, lane = (((k >> 3) & 3) << 4) + lr, jj = k & 7;
        put(base + ((long)((grp*3+ks)*64 + lane))*16 + jj*2, fw[n*CS + k]);
      }
    }
  }
}

// 5-exp 2-rcp cell update, overflow-clamped; returns h, updates c (residual).
DEV float cellupd(float t0, float t1, float t2, float t3, float& c){
  float ei = fexp2(t0);                 // e^{-a_i}
  float ef = fexp2(t1);                 // e^{-a_f}
  float eg = fexp2(t2);                 // e^{2 a_g}
  float eo = fexp2(t3);                 // e^{-a_o}
  float e1 = 1.f + ei, e2 = eg + 1.f, e3 = 1.f + ef;
  float m1 = e1 * e2;
  float num = fmaf(c, m1, (eg - 1.f) * e3);
  float tmp = num * frcp(m1 * e3);      // sigma(f)*c + sigma(i)*tanh(g)
  c += tmp;
  float tc = fminf(tmp, 12.0f);
  float ec = fexp2(tc * PL2E2);
  return (ec - 1.f) * frcp((1.f + eo) * (ec + 1.f));  // sigma(o)*tanh(tmp)
}

// ---------------- main recurrence kernel ----------------
__global__ __launch_bounds__(512, 2) void caurec(
    const float* __restrict__ x,    const float* __restrict__ cs,
    const float* __restrict__ fc1b, const float* __restrict__ fc2b,
    const float* __restrict__ b0i,  const float* __restrict__ b0h,
    const float* __restrict__ b1i,  const float* __restrict__ b1h,
    const float* __restrict__ d1w,  const float* __restrict__ d1b,
    const float* __restrict__ d2w,  const float* __restrict__ d2b,
    const char* __restrict__ ws,    float* __restrict__ out)
{
  __shared__ alignas(16) char L[LDSB];

  const int tid  = threadIdx.x;
  const int wave = tid >> 6, lane = tid & 63, lr = lane & 15, lg = lane >> 4;
  const int n0   = (wave & 3) * 16, mB0 = (wave >> 2) * 32, n1 = wave * 16;
  const int grp  = wave & 3;
  const int rowBase = blockIdx.x * R;
  const int sw8  = (lr & 7) << 4;

  // per-lane bases
  const int rb0   = OH0 + lr*128 + ((lg*16) ^ sw8);    // h0 A-read (+p8 +mt*2048; ^64 = ks1)
  const int rb0w  = rb0 + mB0*128;
  const int rb1   = OH1 + lr*256 + ((lg*16) ^ sw8);    // h1 A-read (^ (ks<<6), +p16 +mt*4096)
  const int xrdb  = OX + (mB0 + lr)*64 + lg*16;        // +px +mt*1024
  const int kadC1 = OKC + wave*256 + lr*16;
  const int kadC0 = OKC + 2048 + grp*256 + lr*16;
  const int cst1  = OH1 + (lg*4)*256 + (((n1 + lr)*2) ^ ((lg & 1) << 6));
  const int cst0  = OH0 + (mB0 + lg*4)*128 + (((n0 + lr)*2) ^ ((lg & 1) << 6));
  const int owxb  = OWX + grp*4096 + lane*16;
  const int owhb  = OWH + grp*8192 + lane*16;
  const int cbase = OC + tid*4;
  const int xr = tid/3, xq = tid - (tid/3)*3;
  const int xst = OX + xr*64 + xq*8;

  // ---- zero: h0 buf1, h1 buf0, x both bufs
  {
    unsigned* W = (unsigned*)L;
    for (int i = tid; i < 2048; i += 512) W[2048  + i] = 0u;   // [8192,16384)
    for (int i = tid; i < 4096; i += 512) W[4096  + i] = 0u;   // [16384,32768)
    for (int i = tid; i < 2048; i += 512) W[12288 + i] = 0u;   // [49152,57344)
  }
  __syncthreads();

  // ---- stage cs -> h1 buf1 (f16, cols 0..127, zeros >=96)
  {
    int r = tid >> 3, cg = (tid & 7) * 16;
    #pragma unroll
    for (int u = 0; u < 2; ++u){
      f16x8 V;
      #pragma unroll
      for (int q4 = 0; q4 < 2; ++q4){
        int col = cg + u*8 + q4*4;
        float4 v = make_float4(0.f,0.f,0.f,0.f);
        if (col < CS) v = *(const float4*)&cs[(size_t)(rowBase + r)*CS + col];
        V[q4*4+0]=(_Float16)v.x; V[q4*4+1]=(_Float16)v.y;
        V[q4*4+2]=(_Float16)v.z; V[q4*4+3]=(_Float16)v.w;
      }
      int ad = OH1 + 16384 + r*256 + (((cg + u*8)*2) ^ ((r & 7) << 4));
      *(f16x8*)(L + ad) = V;
    }
  }
  // x(0) -> x buf0
  if (tid < 192){
    float4 v = *(const float4*)&x[((size_t)(rowBase + xr)*T + 0)*F + xq*4];
    f16x4 w; w[0]=(_Float16)v.x; w[1]=(_Float16)v.y; w[2]=(_Float16)v.z; w[3]=(_Float16)v.w;
    *(f16x4*)(L + xst) = w;
  }
  // wEff
  if (tid < 128){
    float s = 0.f;
    for (int a = 0; a < 64; ++a) s += d2w[a] * d1w[a*128 + tid];
    ((float*)(L + OWE))[tid] = s;
  } else if (tid == 128){
    float s = 0.f;
    for (int a = 0; a < 64; ++a) s += d2w[a] * d1b[a];
    ((float*)(L + OWE))[128] = s + d2b[0];
  }
  // kC (per-gate folded bias constants)
  if (lg == 0){
    f32x4 c1k, c0k;
    #pragma unroll
    for (int g = 0; g < 4; ++g){
      float f = (g == 2) ? PL2E2 : NL2E;
      c1k[g] = f * (b1i[g*128 + n1 + lr] + b1h[g*128 + n1 + lr]);
      c0k[g] = f * (b0i[g*64  + n0 + lr] + b0h[g*64  + n0 + lr]);
    }
    *(f32x4*)(L + kadC1) = c1k;
    *(f32x4*)(L + kadC0) = c0k;   // waves 0-3/4-7 duplicate same data: benign
  }
  // W0x, W0h fragments -> LDS
  #pragma unroll
  for (int k = 0; k < 4; ++k){
    int i = tid + k*512;
    *(long*)(L + OWX + i*8) = *(const long*)(ws + Q0XOFF + i*8);
  }
  #pragma unroll
  for (int k = 0; k < 8; ++k){
    int i = tid + k*512;
    *(long*)(L + OWH + i*8) = *(const long*)(ws + Q0HOFF + i*8);
  }
  // W1 fragments -> registers
  f16x8 WB1[4][6];
  #pragma unroll
  for (int g = 0; g < 4; ++g)
    #pragma unroll
    for (int ks = 0; ks < 6; ++ks)
      WB1[g][ks] = *(const f16x8*)(ws + Q1OFF + ((long)(((wave*4+g)*6+ks)*64 + lane))*16);
  __syncthreads();

  // ---- init GEMMs (cs in h1 buf1) -> c-states in LDS
  {
    const f32x4 Zf = {0.f,0.f,0.f,0.f};
    float bb2 = fc2b[n1 + lr];
    #pragma unroll
    for (int mt = 0; mt < 4; ++mt){
      f32x4 a = Zf;
      #pragma unroll
      for (int ks = 0; ks < 3; ++ks){
        f16x8 A = *(const f16x8*)(L + ((rb1 ^ (ks << 6)) + 16384 + mt*4096));
        f16x8 B = *(const f16x8*)(ws + QF2OFF + ((long)((wave*3+ks)*64 + lane))*16);
        a = MFMA16(A, B, a);
      }
      #pragma unroll
      for (int e = 0; e < 4; ++e)
        *(float*)(L + cbase + (mt*4 + e)*2048) = a[e] + bb2;
    }
    float bb1 = fc1b[n0 + lr];
    #pragma unroll
    for (int mt = 0; mt < 2; ++mt){
      f32x4 a = Zf;
      #pragma unroll
      for (int ks = 0; ks < 3; ++ks){
        f16x8 A = *(const f16x8*)(L + ((rb1 ^ (ks << 6)) + 16384 + mB0*256 + mt*4096));
        f16x8 B = *(const f16x8*)(ws + QF1OFF + ((long)((grp*3+ks)*64 + lane))*16);
        a = MFMA16(A, B, a);
      }
      #pragma unroll
      for (int e = 0; e < 4; ++e)
        *(float*)(L + cbase + ((16 + mt*4) + e)*2048) = a[e] + bb1;
    }
  }
  __syncthreads();

  // ---- tile lambdas
  auto l1_one = [&](int mt, int p8, int p16, int q16){
    const f32x4 Zf = {0.f,0.f,0.f,0.f};
    f32x4 kC = *(const f32x4*)(L + kadC1);
    f16x8 H = *(const f16x8*)(L + (rb0 + p8 + mt*2048));
    f32x4 a0 = MFMA16(H, WB1[0][0], Zf);
    f32x4 a1 = MFMA16(H, WB1[1][0], Zf);
    f32x4 a2 = MFMA16(H, WB1[2][0], Zf);
    f32x4 a3 = MFMA16(H, WB1[3][0], Zf);
    H = *(const f16x8*)(L + ((rb0 ^ 64) + p8 + mt*2048));
    a0 = MFMA16(H, WB1[0][1], a0); a1 = MFMA16(H, WB1[1][1], a1);
    a2 = MFMA16(H, WB1[2][1], a2); a3 = MFMA16(H, WB1[3][1], a3);
    #pragma unroll
    for (int ks = 0; ks < 4; ++ks){
      H = *(const f16x8*)(L + ((rb1 ^ (ks << 6)) + p16 + mt*4096));
      a0 = MFMA16(H, WB1[0][2+ks], a0); a1 = MFMA16(H, WB1[1][2+ks], a1);
      a2 = MFMA16(H, WB1[2][2+ks], a2); a3 = MFMA16(H, WB1[3][2+ks], a3);
    }
    const int sb = cst1 + q16 + mt*4096;
    #pragma unroll
    for (int e = 0; e < 4; ++e){
      float t0 = fmaf(a0[e], NL2E,  kC[0]);
      float t1 = fmaf(a1[e], NL2E,  kC[1]);
      float t2 = fmaf(a2[e], PL2E2, kC[2]);
      float t3 = fmaf(a3[e], NL2E,  kC[3]);
      float cc = *(const float*)(L + cbase + (mt*4 + e)*2048);
      float h = cellupd(t0, t1, t2, t3, cc);
      *(float*)(L + cbase + (mt*4 + e)*2048) = cc;
      *(_Float16*)(L + ((sb + e*256) ^ (e << 4))) = (_Float16)h;
    }
  };

  auto l0_one = [&](int mt, int p8, int px, int q8){
    const f32x4 Zf = {0.f,0.f,0.f,0.f};
    f32x4 kC = *(const f32x4*)(L + kadC0);
    f16x8 X  = *(const f16x8*)(L + (xrdb + px + mt*1024));
    f16x8 H0 = *(const f16x8*)(L + (rb0w + p8 + mt*2048));
    f16x8 H1 = *(const f16x8*)(L + ((rb0w ^ 64) + p8 + mt*2048));
    f32x4 a0, a1, a2, a3;
    {
      f16x8 W0 = *(const f16x8*)(L + owhb + 0*2048);
      f16x8 W1 = *(const f16x8*)(L + owhb + 0*2048 + 1024);
      f16x8 Wx = *(const f16x8*)(L + owxb + 0*1024);
      a0 = MFMA16(H0, W0, Zf); a0 = MFMA16(H1, W1, a0); a0 = MFMA16(X, Wx, a0);
    }
    {
      f16x8 W0 = *(const f16x8*)(L + owhb + 1*2048);
      f16x8 W1 = *(const f16x8*)(L + owhb + 1*2048 + 1024);
      f16x8 Wx = *(const f16x8*)(L + owxb + 1*1024);
      a1 = MFMA16(H0, W0, Zf); a1 = MFMA16(H1, W1, a1); a1 = MFMA16(X, Wx, a1);
    }
    {
      f16x8 W0 = *(const f16x8*)(L + owhb + 2*2048);
      f16x8 W1 = *(const f16x8*)(L + owhb + 2*2048 + 1024);
      f16x8 Wx = *(const f16x8*)(L + owxb + 2*1024);
      a2 = MFMA16(H0, W0, Zf); a2 = MFMA16(H1, W1, a2); a2 = MFMA16(X, Wx, a2);
    }
    {
      f16x8 W0 = *(const f16x8*)(L + owhb + 3*2048);
      f16x8 W1 = *(const f16x8*)(L + owhb + 3*2048 + 1024);
      f16x8 Wx = *(const f16x8*)(L + owxb + 3*1024);
      a3 = MFMA16(H0, W0, Zf); a3 = MFMA16(H1, W1, a3); a3 = MFMA16(X, Wx, a3);
    }
    const int sb = cst0 + q8 + mt*2048;
    #pragma unroll
    for (int e = 0; e < 4; ++e){
      float t0 = fmaf(a0[e], NL2E,  kC[0]);
      float t1 = fmaf(a1[e], NL2E,  kC[1]);
      float t2 = fmaf(a2[e], PL2E2, kC[2]);
      float t3 = fmaf(a3[e], NL2E,  kC[3]);
      float cc = *(const float*)(L + cbase + ((16 + mt*4) + e)*2048);
      float h = cellupd(t0, t1, t2, t3, cc);
      *(float*)(L + cbase + ((16 + mt*4) + e)*2048) = cc;
      *(_Float16*)(L + ((sb + e*128) ^ (e << 4))) = (_Float16)h;
    }
  };

  // ---- pre-loop: L0(0): h0(-1)=zeros(buf1), x(0)(buf0) -> h0(0)->buf0; stage x(1)->buf1
  {
    float4 xv; const bool doX = tid < 192;
    if (doX) xv = *(const float4*)&x[((size_t)(rowBase + xr)*T + 1)*F + xq*4];
    l0_one(0, 8192, 0, 0);
    l0_one(1, 8192, 0, 0);
    if (doX){
      f16x4 w; w[0]=(_Float16)xv.x; w[1]=(_Float16)xv.y; w[2]=(_Float16)xv.z; w[3]=(_Float16)xv.w;
      *(f16x4*)(L + xst + 4096) = w;
    }
    __syncthreads();
  }

  // ---- main loop: M(i) = L1(i) + L0(i+1); 1 barrier/step
  for (int j = 0; j < 7; ++j){
    { // M(2j): reads buf0 (h0,h1), x buf1; writes buf1; stage x(2j+2)->buf0
      float4 xv; const bool doX = tid < 192;
      if (doX) xv = *(const float4*)&x[((size_t)(rowBase + xr)*T + (2*j + 2))*F + xq*4];
      l1_one(0, 0, 0, 16384);
      l1_one(1, 0, 0, 16384);
      l0_one(0, 0, 4096, 8192);
      l1_one(2, 0, 0, 16384);
      l0_one(1, 0, 4096, 8192);
      l1_one(3, 0, 0, 16384);
      if (doX){
        f16x4 w; w[0]=(_Float16)xv.x; w[1]=(_Float16)xv.y; w[2]=(_Float16)xv.z; w[3]=(_Float16)xv.w;
        *(f16x4*)(L + xst) = w;
      }
      __syncthreads();
    }
    { // M(2j+1): reads buf1, x buf0; writes buf0; stage x(2j+3)->buf1 (j<6)
      float4 xv; const bool doX = (j < 6) && (tid < 192);
      if (doX) xv = *(const float4*)&x[((size_t)(rowBase + xr)*T + (2*j + 3))*F + xq*4];
      l1_one(0, 8192, 16384, 0);
      l1_one(1, 8192, 16384, 0);
      l0_one(0, 8192, 0, 0);
      l1_one(2, 8192, 16384, 0);
      l0_one(1, 8192, 0, 0);
      l1_one(3, 8192, 16384, 0);
      if (doX){
        f16x4 w; w[0]=(_Float16)xv.x; w[1]=(_Float16)xv.y; w[2]=(_Float16)xv.z; w[3]=(_Float16)xv.w;
        *(f16x4*)(L + xst + 4096) = w;
      }
      __syncthreads();
    }
  }

  // ---- final: L1(14) (reads buf0) -> h1(15) into buf1
  {
    l1_one(0, 0, 0, 16384);
    l1_one(1, 0, 0, 16384);
    l1_one(2, 0, 0, 16384);
    l1_one(3, 0, 0, 16384);
    __syncthreads();
  }

  // ---- epilogue: pred = h1 . w_eff + b_eff (h1 f16 in buf1)
  {
    int r = tid >> 3, s = tid & 7;
    const float* wE = (const float*)(L + OWE);
    float sum = 0.f;
    #pragma unroll
    for (int cc = 0; cc < 16; ++cc){
      int c = s*16 + cc;
      const char* pe = L + OH1 + 16384 + r*256 + ((c*2) ^ ((r & 7) << 4));
      sum += (float)(*(const _Float16*)pe) * wE[c];
    }
    sum += __shfl_down(sum, 4);
    sum += __shfl_down(sum, 2);
    sum += __shfl_down(sum, 1);
    if (s == 0) out[rowBase + r] = sum + wE[128];
  }
}

extern "C" void kernel_launch(void* const* d_in, const int* in_sizes, int n_in,
                              void* d_out, int out_size, void* d_ws, size_t ws_size,
                              hipStream_t stream) {
  const float* x    = (const float*)d_in[0];
  const float* cs   = (const float*)d_in[1];
  const float* fc1w = (const float*)d_in[2];
  const float* fc1b = (const float*)d_in[3];
  const float* fc2w = (const float*)d_in[4];
  const float* fc2b = (const float*)d_in[5];
  const float* w0i  = (const float*)d_in[6];
  const float* w0h  = (const float*)d_in[7];
  const float* b0i  = (const float*)d_in[8];
  const float* b0h  = (const float*)d_in[9];
  const float* w1i  = (const float*)d_in[10];
  const float* w1h  = (const float*)d_in[11];
  const float* b1i  = (const float*)d_in[12];
  const float* b1h  = (const float*)d_in[13];
  const float* d1w  = (const float*)d_in[14];
  const float* d1b  = (const float*)d_in[15];
  const float* d2w  = (const float*)d_in[16];
  const float* d2b  = (const float*)d_in[17];

  char* ws = (char*)d_ws;
  prequant<<<960, 64, 0, stream>>>(fc1w, fc2w, w0i, w0h, w1i, w1h, ws);

  const int Btot = in_sizes[0] / (T * F);   // 131072
  const int grid = Btot / R;                // 2048
  caurec<<<grid, 512, 0, stream>>>(x, cs, fc1b, fc2b, b0i, b0h, b1i, b1h,
                                   d1w, d1b, d2w, d2b, ws, (float*)d_out);
}